// Round 18
// baseline (143.706 us; speedup 1.0000x reference)
//
#include <hip/hip_runtime.h>
#include <hip/hip_bf16.h>

#define DEV static __device__ __forceinline__

typedef __bf16 bf16x8 __attribute__((ext_vector_type(8)));
typedef __bf16 bf16x4 __attribute__((ext_vector_type(4)));
typedef float  f32x4  __attribute__((ext_vector_type(4)));

// B=16, C=128, H=W=64, HW=4096. qkv channels: q 0..127, k 128..255, v 256..511

// Hand-rolled conversions: measured faster than native (__bf16) casts (R6 regression:
// k67 40.8 -> 58.9 us with native casts; integer RNE restores it).
DEV float bf2f(__bf16 b) {
    unsigned short h = __builtin_bit_cast(unsigned short, b);
    unsigned int u = ((unsigned int)h) << 16;
    return __builtin_bit_cast(float, u);
}
DEV __bf16 f2bf(float f) {
    unsigned int u = __builtin_bit_cast(unsigned int, f);
    unsigned int r = (u + 0x7fffu + ((u >> 16) & 1u)) >> 16;
    unsigned short h = (unsigned short)r;
    return __builtin_bit_cast(__bf16, h);
}
DEV __bf16 bf_zero() { return __builtin_bit_cast(__bf16, (unsigned short)0); }

// XOR swizzle (elements): k ^= (row&7)<<3  (== byte ^ ((row&7)<<4); slot ^= row&7 in 16B units)
DEV int swz(int row, int k) { return k ^ ((row & 7) << 3); }

// async global->LDS, 16B per lane; LDS dest = uniform base + lane*16 (linear 1KB/wave-issue)
DEV void gload_lds16(const void* g, void* l) {
    __builtin_amdgcn_global_load_lds((const __attribute__((address_space(1))) unsigned int*)g,
                                     (__attribute__((address_space(3))) unsigned int*)l, 16, 0, 0);
}

// MFMA tile: sA rows -> out rows ((lane>>4)*4+r), sB rows -> out cols (lane&15)
template <int RK, int MREP, int NREP>
DEV void mfma_tile(const __bf16* sA, const __bf16* sB, f32x4 (&acc)[MREP][NREP],
                   int lane, int arow0, int brow0) {
    #pragma unroll
    for (int kk = 0; kk < RK; kk += 32) {
        const int krow = kk + ((lane >> 4) << 3);
        bf16x8 a[MREP], b[NREP];
        #pragma unroll
        for (int i = 0; i < MREP; ++i) {
            const int ra = arow0 + i * 16 + (lane & 15);
            a[i] = *(const bf16x8*)&sA[ra * RK + swz(ra, krow)];
        }
        #pragma unroll
        for (int j = 0; j < NREP; ++j) {
            const int rb = brow0 + j * 16 + (lane & 15);
            b[j] = *(const bf16x8*)&sB[rb * RK + swz(rb, krow)];
        }
        #pragma unroll
        for (int i = 0; i < MREP; ++i)
            #pragma unroll
            for (int j = 0; j < NREP; ++j)
                acc[i][j] = __builtin_amdgcn_mfma_f32_16x16x32_bf16(a[i], b[j], acc[i][j], 0, 0, 0);
    }
}

// ---------- K0: fold BN scales into weights ----------
__global__ __launch_bounds__(256) void k0_fold(
    const float* __restrict__ wq, const float* __restrict__ sq, const float* __restrict__ bq,
    const float* __restrict__ wk, const float* __restrict__ sk, const float* __restrict__ bk,
    const float* __restrict__ wv, const float* __restrict__ sv, const float* __restrict__ bv,
    const float* __restrict__ wdw, const float* __restrict__ sdw, const float* __restrict__ bdw,
    const float* __restrict__ wpw, const float* __restrict__ spw, const float* __restrict__ bpw,
    const float* __restrict__ wrow, const float* __restrict__ srow, const float* __restrict__ brow,
    const float* __restrict__ wcol, const float* __restrict__ scol, const float* __restrict__ bcol,
    const float* __restrict__ wproj, const float* __restrict__ sproj, const float* __restrict__ bproj,
    __bf16* __restrict__ wf_qkv, float* __restrict__ bias_qkv,
    float* __restrict__ wdw_t, float* __restrict__ bias_dw,
    __bf16* __restrict__ wpw_f, float* __restrict__ bias_pw,
    __bf16* __restrict__ wrc, float* __restrict__ bias_row, float* __restrict__ bias_col,
    __bf16* __restrict__ wproj_f, float* __restrict__ bias_proj) {
    int id = blockIdx.x * 256 + threadIdx.x;
    if (id < 65536) {  // qkv weights [512][128]
        int co = id >> 7, ci = id & 127;
        float w, s, b;
        if (co < 128)      { w = wq[co * 128 + ci];        s = sq[co];        b = bq[co]; }
        else if (co < 256) { int c = co - 128; w = wk[c * 128 + ci]; s = sk[c]; b = bk[c]; }
        else               { int c = co - 256; w = wv[c * 128 + ci]; s = sv[c]; b = bv[c]; }
        wf_qkv[id] = f2bf(w * s);
        if (ci == 0) bias_qkv[co] = b;
        return;
    }
    id -= 65536;
    if (id < 4608) {  // dw [512][9] -> tap-major wdw_t[9][512]
        int c = id / 9, tap = id - c * 9;
        wdw_t[tap * 512 + c] = wdw[id] * sdw[c];
        if (tap == 0) bias_dw[c] = bdw[c];
        return;
    }
    id -= 4608;
    if (id < 65536) {  // pw [128][512]
        int co = id >> 9;
        wpw_f[id] = f2bf(wpw[id] * spw[co]);
        if ((id & 511) == 0) bias_pw[co] = bpw[co];
        return;
    }
    id -= 65536;
    if (id < 65536) {  // row [256][256] -> wrc[0]
        int co = id >> 8;
        wrc[id] = f2bf(wrow[id] * srow[co]);
        if ((id & 255) == 0) bias_row[co] = brow[co];
        return;
    }
    id -= 65536;
    if (id < 65536) {  // col [256][256] -> wrc[1]
        int co = id >> 8;
        wrc[65536 + id] = f2bf(wcol[id] * scol[co]);
        if ((id & 255) == 0) bias_col[co] = bcol[co];
        return;
    }
    id -= 65536;
    if (id < 32768) {  // proj [128][256]
        int co = id >> 8;
        wproj_f[id] = f2bf(wproj[id] * sproj[co]);
        if ((id & 255) == 0) bias_proj[co] = bproj[co];
        return;
    }
}

// ---------- KM: x row/col means, single coalesced pass -> xmT [b][2][64 pos][128 ci] ----------
__global__ __launch_bounds__(256) void kM_xmean(const float* __restrict__ x,
                                                float* __restrict__ xmT) {
    const int b = blockIdx.x;
    const int wv = threadIdx.x >> 6, lane = threadIdx.x & 63;
    const int c = blockIdx.y * 4 + wv;
    __shared__ float sRow[4][64];
    __shared__ float sCol[4][64];
    const float* p = x + ((size_t)b * 128 + c) * 4096;
    float cacc0 = 0.f, cacc1 = 0.f, cacc2 = 0.f, cacc3 = 0.f;
    #pragma unroll
    for (int g = 0; g < 16; ++g) {
        f32x4 v = *(const f32x4*)&p[(g * 64 + lane) * 4];
        cacc0 += v[0]; cacc1 += v[1]; cacc2 += v[2]; cacc3 += v[3];
        float s = v[0] + v[1] + v[2] + v[3];
        s += __shfl_xor(s, 1);
        s += __shfl_xor(s, 2);
        s += __shfl_xor(s, 4);
        s += __shfl_xor(s, 8);
        if ((lane & 15) == 0) sRow[wv][g * 4 + (lane >> 4)] = s;
    }
    cacc0 += __shfl_xor(cacc0, 16); cacc0 += __shfl_xor(cacc0, 32);
    cacc1 += __shfl_xor(cacc1, 16); cacc1 += __shfl_xor(cacc1, 32);
    cacc2 += __shfl_xor(cacc2, 16); cacc2 += __shfl_xor(cacc2, 32);
    cacc3 += __shfl_xor(cacc3, 16); cacc3 += __shfl_xor(cacc3, 32);
    if (lane < 16) {
        sCol[wv][lane * 4]     = cacc0;
        sCol[wv][lane * 4 + 1] = cacc1;
        sCol[wv][lane * 4 + 2] = cacc2;
        sCol[wv][lane * 4 + 3] = cacc3;
    }
    __syncthreads();
    xmT[((size_t)(b * 2 + 0) * 64 + lane) * 128 + c] = sRow[wv][lane] * (1.f / 64.f);
    xmT[((size_t)(b * 2 + 1) * 64 + lane) * 128 + c] = sCol[wv][lane] * (1.f / 64.f);
}

// ---------- KQM: qkv means = wf_qkv @ xmean + bias -> qm [b][2][512][64] f32 ----------
__global__ __launch_bounds__(256) void kQM(const __bf16* __restrict__ wf,
                                           const float* __restrict__ bias,
                                           const float* __restrict__ xmT,
                                           float* __restrict__ qm) {
    const int b = blockIdx.x, axis = blockIdx.y, cot = blockIdx.z;
    __shared__ __bf16 sA[128 * 128];
    __shared__ __bf16 sB[64 * 128];
    const int t = threadIdx.x, lane = t & 63, wave = t >> 6;
    #pragma unroll
    for (int u = 0; u < 8; ++u) {
        int unit = t + u * 256; int cc = unit & 15, r = unit >> 4;
        *(bf16x8*)&sA[r * 128 + swz(r, cc * 8)] =
            *(const bf16x8*)&wf[(size_t)(cot * 128 + r) * 128 + cc * 8];
    }
    const float* xb = xmT + (size_t)(b * 2 + axis) * 64 * 128;
    #pragma unroll
    for (int u = 0; u < 4; ++u) {
        int unit = t + u * 256; int cc = unit & 15, r = unit >> 4;
        f32x4 v0 = *(const f32x4*)&xb[r * 128 + cc * 8];
        f32x4 v1 = *(const f32x4*)&xb[r * 128 + cc * 8 + 4];
        bf16x8 o;
        o[0] = f2bf(v0[0]); o[1] = f2bf(v0[1]); o[2] = f2bf(v0[2]); o[3] = f2bf(v0[3]);
        o[4] = f2bf(v1[0]); o[5] = f2bf(v1[1]); o[6] = f2bf(v1[2]); o[7] = f2bf(v1[3]);
        *(bf16x8*)&sB[r * 128 + swz(r, cc * 8)] = o;
    }
    __syncthreads();
    f32x4 acc[4][2];
    #pragma unroll
    for (int i = 0; i < 4; ++i)
        #pragma unroll
        for (int j = 0; j < 2; ++j) acc[i][j] = (f32x4){0.f, 0.f, 0.f, 0.f};
    mfma_tile<128, 4, 2>(sA, sB, acc, lane, (wave & 1) * 64, (wave >> 1) * 32);
    #pragma unroll
    for (int i = 0; i < 4; ++i)
        #pragma unroll
        for (int r = 0; r < 4; ++r)
            #pragma unroll
            for (int j = 0; j < 2; ++j) {
                int c = cot * 128 + (wave & 1) * 64 + i * 16 + ((lane >> 4) * 4 + r);
                int pos = (wave >> 1) * 32 + j * 16 + (lane & 15);
                qm[((size_t)(b * 2 + axis) * 512 + c) * 64 + pos] = acc[i][j][r] + bias[c];
            }
}

// ---------- K3: axial attention -> attnT bf16 [b2][64 pos][256 ci], relu'd ----------
DEV float interp16(const float* __restrict__ p, int i) {
    float c = 0.25f * (float)i - 0.375f;
    c = fminf(fmaxf(c, 0.f), 15.f);
    const int lo = (int)c;
    const int hi = min(lo + 1, 15);
    const float f = c - (float)lo;
    return p[lo] * (1.f - f) + p[hi] * f;
}

__global__ __launch_bounds__(64) void k3_attn(const float* __restrict__ qm,
                                              const float* __restrict__ pe_rq,
                                              const float* __restrict__ pe_rk,
                                              const float* __restrict__ pe_cq,
                                              const float* __restrict__ pe_ck,
                                              __bf16* __restrict__ attnT) {
    const int b = blockIdx.x, axis = blockIdx.y, head = blockIdx.z;
    const float* peq = axis ? pe_cq : pe_rq;
    const float* pek = axis ? pe_ck : pe_rk;
    const int lane = threadIdx.x;
    __shared__ float sQ[64][16];
    __shared__ float sK[16][64];
    __shared__ float sV[64][32];
    const float* mb = qm + (size_t)(b * 2 + axis) * 512 * 64;
    #pragma unroll
    for (int kd = 0; kd < 16; ++kd) {
        const int c = head * 16 + kd;
        sQ[lane][kd] = mb[c * 64 + lane] + interp16(peq + c * 16, lane);
        sK[kd][lane] = mb[(128 + c) * 64 + lane] + interp16(pek + c * 16, lane);
    }
    #pragma unroll
    for (int d = 0; d < 32; ++d) {
        const int c = 256 + head * 32 + d;
        sV[lane][d] = mb[c * 64 + lane];
    }
    __syncthreads();
    float qr[16];
    #pragma unroll
    for (int kd = 0; kd < 16; ++kd) qr[kd] = sQ[lane][kd];
    float s[64];
    #pragma unroll
    for (int j = 0; j < 64; ++j) {
        float a = 0.f;
        #pragma unroll
        for (int kd = 0; kd < 16; ++kd) a += qr[kd] * sK[kd][j];
        s[j] = a * 0.25f;
    }
    float m = -1e30f;
    #pragma unroll
    for (int j = 0; j < 64; ++j) m = fmaxf(m, s[j]);
    float sum = 0.f;
    #pragma unroll
    for (int j = 0; j < 64; ++j) { s[j] = __expf(s[j] - m); sum += s[j]; }
    const float inv = 1.f / sum;
    float O[32];
    #pragma unroll
    for (int d = 0; d < 32; ++d) O[d] = 0.f;
    #pragma unroll
    for (int j = 0; j < 64; ++j) {
        const float pj = s[j] * inv;
        #pragma unroll
        for (int d = 0; d < 32; ++d) O[d] += pj * sV[j][d];
    }
    __bf16* ob = attnT + ((size_t)(b * 2 + axis) * 64 + lane) * 256 + head * 32;
    #pragma unroll
    for (int d8 = 0; d8 < 4; ++d8) {
        bf16x8 o;
        #pragma unroll
        for (int j = 0; j < 8; ++j) o[j] = f2bf(fmaxf(O[d8 * 8 + j], 0.f));
        *(bf16x8*)&ob[d8 * 8] = o;
    }
}

// ---------- K4: wrow/wcol 1x1 conv via MFMA -> xrc [b][2][64 pos][256 co] f32 ----------
__global__ __launch_bounds__(256) void k4_rcconv(const __bf16* __restrict__ attnT,
                                                 const __bf16* __restrict__ wrc,
                                                 const float* __restrict__ brow,
                                                 const float* __restrict__ bcol,
                                                 float* __restrict__ xrc) {
    const int b = blockIdx.x, axis = blockIdx.y, cot = blockIdx.z;
    __shared__ __bf16 sA[128 * 128];           // 32 KB, reused as f32 sT in epilogue
    __shared__ __bf16 sB[2][64 * 128];         // 32 KB: both K-chunks of attnT tile
    const int t = threadIdx.x, lane = t & 63, wave = t >> 6;
    const float* bias = axis ? bcol : brow;
    const __bf16* src = attnT + (size_t)(b * 2 + axis) * 64 * 256;
    #pragma unroll
    for (int u = 0; u < 8; ++u) {
        int unit = t + u * 256;                // 2048 units
        int cj = unit & 31, r = unit >> 5;     // k = cj*8 in 0..255
        int k = cj * 8, chunk = k >> 7, kin = k & 127;
        *(bf16x8*)&sB[chunk][r * 128 + swz(r, kin)] = *(const bf16x8*)&src[r * 256 + k];
    }
    f32x4 acc[4][2];
    #pragma unroll
    for (int i = 0; i < 4; ++i)
        #pragma unroll
        for (int j = 0; j < 2; ++j) acc[i][j] = (f32x4){0.f, 0.f, 0.f, 0.f};
    for (int kc = 0; kc < 2; ++kc) {
        __syncthreads();
        #pragma unroll
        for (int u = 0; u < 8; ++u) {
            int unit = t + u * 256; int cc = unit & 15, r = unit >> 4;
            *(bf16x8*)&sA[r * 128 + swz(r, cc * 8)] =
                *(const bf16x8*)&wrc[(size_t)(axis * 256 + cot * 128 + r) * 256 + kc * 128 + cc * 8];
        }
        __syncthreads();
        mfma_tile<128, 4, 2>(sA, sB[kc], acc, lane, (wave & 1) * 64, (wave >> 1) * 32);
    }
    __syncthreads();
    float* sT = (float*)sA;  // [64 pos][128 co'], co' XOR-swizzled by (pos&7)<<2
    #pragma unroll
    for (int i = 0; i < 4; ++i)
        #pragma unroll
        for (int r = 0; r < 4; ++r)
            #pragma unroll
            for (int j = 0; j < 2; ++j) {
                int cop = (wave & 1) * 64 + i * 16 + ((lane >> 4) * 4 + r);
                int pos = (wave >> 1) * 32 + j * 16 + (lane & 15);
                sT[pos * 128 + (cop ^ ((pos & 7) << 2))] = acc[i][j][r] + bias[cot * 128 + cop];
            }
    __syncthreads();
    #pragma unroll
    for (int u = 0; u < 8; ++u) {
        int unit = t + u * 256;                // 2048 f32x4 units
        int q = unit & 31, pos = unit >> 5;
        f32x4 v = *(const f32x4*)&sT[pos * 128 + ((q * 4) ^ ((pos & 7) << 2))];
        *(f32x4*)&xrc[((size_t)(b * 2 + axis) * 64 + pos) * 256 + cot * 128 + q * 4] = v;
    }
}

// ---------- K1: qkv GEMM reading x directly (kT fused in) -> qkv [b][4096 n][512 co] ----------
__global__ __launch_bounds__(256) void k1_qkv(const float* __restrict__ x,
                                              const __bf16* __restrict__ wf,
                                              const float* __restrict__ bias,
                                              __bf16* __restrict__ qkv) {
    const int b = blockIdx.x, nt = blockIdx.y;
    __shared__ __bf16 sA[128 * 128];  // stage-0: [ci][n] n-swizzled; then weights; then sT
    __shared__ __bf16 sB[128 * 128];  // x tile transposed [n][ci] (staged once)
    const int t = threadIdx.x, lane = t & 63, wave = t >> 6;
    const int n0 = nt * 128;
    const float* xb = x + (size_t)b * 128 * 4096;
    // phase 0a: coalesced f32 read of x[ci][n0+n] -> sA[ci][n] (n XOR-swizzled by (ci>>3)&7)
    #pragma unroll
    for (int u = 0; u < 16; ++u) {
        int unit = t + u * 256;
        int ci = unit >> 5, n4 = (unit & 31) * 4;
        f32x4 v = *(const f32x4*)&xb[(size_t)ci * 4096 + n0 + n4];
        bf16x4 e;
        e[0] = f2bf(v[0]); e[1] = f2bf(v[1]); e[2] = f2bf(v[2]); e[3] = f2bf(v[3]);
        *(bf16x4*)&sA[ci * 128 + (n4 ^ (((ci >> 3) & 7) << 3))] = e;
    }
    __syncthreads();
    // phase 0b: transpose into sB[n][ci] (ci XOR-swizzled by swz(n,..))
    #pragma unroll
    for (int u = 0; u < 8; ++u) {
        int unit = t + u * 256;
        int cg = unit & 15, n = unit >> 4;
        bf16x8 o;
        #pragma unroll
        for (int j = 0; j < 8; ++j) {
            int ci = cg * 8 + j;
            o[j] = sA[ci * 128 + (n ^ (((ci >> 3) & 7) << 3))];
        }
        *(bf16x8*)&sB[n * 128 + swz(n, cg * 8)] = o;
    }
    for (int cot = 0; cot < 4; ++cot) {
        __syncthreads();
        #pragma unroll
        for (int u = 0; u < 8; ++u) {
            int unit = t + u * 256; int cc = unit & 15, r = unit >> 4;
            *(bf16x8*)&sA[r * 128 + swz(r, cc * 8)] =
                *(const bf16x8*)&wf[(size_t)(cot * 128 + r) * 128 + cc * 8];
        }
        __syncthreads();
        f32x4 acc[4][4];
        #pragma unroll
        for (int i = 0; i < 4; ++i)
            #pragma unroll
            for (int j = 0; j < 4; ++j) acc[i][j] = (f32x4){0.f, 0.f, 0.f, 0.f};
        mfma_tile<128, 4, 4>(sA, sB, acc, lane, (wave >> 1) * 64, (wave & 1) * 64);
        __syncthreads();
        __bf16* sT = sA;  // [n][128 co], co XOR-swizzled by (n&7)<<3
        #pragma unroll
        for (int i = 0; i < 4; ++i)
            #pragma unroll
            for (int r = 0; r < 4; ++r)
                #pragma unroll
                for (int j = 0; j < 4; ++j) {
                    int co = (wave >> 1) * 64 + i * 16 + ((lane >> 4) * 4 + r);
                    int n  = (wave & 1) * 64 + j * 16 + (lane & 15);
                    sT[n * 128 + (co ^ ((n & 7) << 3))] = f2bf(acc[i][j][r] + bias[cot * 128 + co]);
                }
        __syncthreads();
        #pragma unroll
        for (int u = 0; u < 8; ++u) {
            int unit = t + u * 256; int cc = unit & 15, n = unit >> 4;
            bf16x8 vv = *(bf16x8*)&sT[n * 128 + ((cc * 8) ^ ((n & 7) << 3))];
            *(bf16x8*)&qkv[((size_t)b * 4096 + n0 + n) * 512 + cot * 128 + cc * 8] = vv;
        }
    }
}

// ---------- K5: depthwise 3x3 + BN + relu, bf16 LDS + register row-reuse ----------
__global__ __launch_bounds__(256) void k5_dw(const __bf16* __restrict__ qkv,
                                             const float* __restrict__ wdw_t,
                                             const float* __restrict__ bdw,
                                             __bf16* __restrict__ dwo) {
    const int b = blockIdx.x, h0 = blockIdx.y * 4, cs = blockIdx.z * 32;
    __shared__ __bf16 sH[6][66][32];  // 25.3 KB
    const int t = threadIdx.x;
    const int w = t >> 2, cg = t & 3;  // cg: group of 8 channels
    #pragma unroll
    for (int row = 0; row < 6; ++row) {
        int h = h0 + row - 1;
        bf16x8 v;
        #pragma unroll
        for (int j = 0; j < 8; ++j) v[j] = bf_zero();
        if (h >= 0 && h < 64)
            v = *(const bf16x8*)&qkv[((size_t)b * 4096 + h * 64 + w) * 512 + cs + cg * 8];
        *(bf16x8*)&sH[row][w + 1][cg * 8] = v;
    }
    if (t < 192) {  // zero halo columns wz=0 and wz=65
        int row = t >> 5, c = t & 31;
        sH[row][0][c] = bf_zero();
        sH[row][65][c] = bf_zero();
    }
    float acc[4][8];
    {
        float bb[8];
        #pragma unroll
        for (int j = 0; j < 8; ++j) bb[j] = bdw[cs + cg * 8 + j];
        #pragma unroll
        for (int h = 0; h < 4; ++h)
            #pragma unroll
            for (int j = 0; j < 8; ++j) acc[h][j] = bb[j];
    }
    __syncthreads();
    #pragma unroll
    for (int dx = 0; dx < 3; ++dx) {
        f32x4 w0[3], w1[3];
        #pragma unroll
        for (int dy = 0; dy < 3; ++dy) {
            const float* wp = &wdw_t[(dy * 3 + dx) * 512 + cs + cg * 8];
            w0[dy] = *(const f32x4*)wp;
            w1[dy] = *(const f32x4*)(wp + 4);
        }
        float r[6][8];
        #pragma unroll
        for (int row = 0; row < 6; ++row) {
            bf16x8 v = *(const bf16x8*)&sH[row][w + dx][cg * 8];
            #pragma unroll
            for (int j = 0; j < 8; ++j) r[row][j] = bf2f(v[j]);
        }
        #pragma unroll
        for (int h = 0; h < 4; ++h)
            #pragma unroll
            for (int dy = 0; dy < 3; ++dy) {
                #pragma unroll
                for (int j = 0; j < 4; ++j) {
                    acc[h][j]     += w0[dy][j] * r[h + dy][j];
                    acc[h][4 + j] += w1[dy][j] * r[h + dy][4 + j];
                }
            }
    }
    #pragma unroll
    for (int h = 0; h < 4; ++h) {
        bf16x8 o;
        #pragma unroll
        for (int j = 0; j < 8; ++j) o[j] = f2bf(fmaxf(acc[h][j], 0.f));
        *(bf16x8*)&dwo[((size_t)b * 4096 + (h0 + h) * 64 + w) * 512 + cs + cg * 8] = o;
    }
}

// ---------- K67: fused pw GEMM + proj GEMM + gate; 512 thr, XCD swizzle, vec epilogue ----------
__global__ __launch_bounds__(512) void k67_fused(const __bf16* __restrict__ dws,
                                                 const __bf16* __restrict__ wpw,
                                                 const float* __restrict__ bias_pw,
                                                 const __bf16* __restrict__ qkv,
                                                 const __bf16* __restrict__ wproj,
                                                 const float* __restrict__ bias_proj,
                                                 const float* __restrict__ xrc,
                                                 float* __restrict__ out) {
    // XCD-aware remap: 1024 blocks, 8 XCDs -> each XCD gets 128 consecutive (b,nt) slots
    const int bid = blockIdx.x;
    const int sw = (bid & 7) * 128 + (bid >> 3);
    const int b = sw >> 6, nt = sw & 63;
    __shared__ __bf16 sA[128 * 128];
    __shared__ __bf16 sB[64 * 128];
    const int t = threadIdx.x, lane = t & 63, wave = t >> 6;   // 8 waves
    const int arow0 = (wave & 3) * 32, brow0 = (wave >> 2) * 32;  // 4x2 quadrants of 32x32
    const float* xr = xrc + (size_t)(b * 2 + 0) * 64 * 256;
    const float* xc = xrc + (size_t)(b * 2 + 1) * 64 * 256;
    f32x4 acc_pw[2][2], acc_pj[2][2];
    #pragma unroll
    for (int i = 0; i < 2; ++i)
        #pragma unroll
        for (int j = 0; j < 2; ++j) {
            acc_pw[i][j] = (f32x4){0.f, 0.f, 0.f, 0.f};
            acc_pj[i][j] = (f32x4){0.f, 0.f, 0.f, 0.f};
        }
    // phase 1: pw GEMM, K=512; both operands via async global_load_lds (pre-swizzled src)
    for (int kc = 0; kc < 4; ++kc) {
        __syncthreads();
        #pragma unroll
        for (int u = 0; u < 4; ++u) {          // sA: 32 chunks of 1KB over 8 waves
            int r0 = (wave * 4 + u) * 4;
            int row = r0 + (lane >> 4);
            int slot = (lane & 15) ^ (row & 7);
            gload_lds16(&wpw[(size_t)row * 512 + kc * 128 + slot * 8], &sA[r0 * 128]);
        }
        #pragma unroll
        for (int u = 0; u < 2; ++u) {          // sB: 16 chunks of 1KB
            int r0 = (wave * 2 + u) * 4;
            int row = r0 + (lane >> 4);
            int slot = (lane & 15) ^ (row & 7);
            gload_lds16(&dws[((size_t)b * 4096 + nt * 64 + row) * 512 + kc * 128 + slot * 8],
                        &sB[r0 * 128]);
        }
        __syncthreads();
        mfma_tile<128, 2, 2>(sA, sB, acc_pw, lane, arow0, brow0);
    }
    // phase 2: proj GEMM on relu(v + xx_row + xx_col), K=256 (sA async; sB computed)
    for (int kc = 0; kc < 2; ++kc) {
        __syncthreads();
        #pragma unroll
        for (int u = 0; u < 4; ++u) {
            int r0 = (wave * 4 + u) * 4;
            int row = r0 + (lane >> 4);
            int slot = (lane & 15) ^ (row & 7);
            gload_lds16(&wproj[(size_t)row * 256 + kc * 128 + slot * 8], &sA[r0 * 128]);
        }
        #pragma unroll
        for (int u = 0; u < 2; ++u) {          // 1024 units over 512 threads
            int unit = t + u * 512; int cc = unit & 15, r = unit >> 4;
            int n = nt * 64 + r, h = n >> 6, ww = n & 63;
            int k = kc * 128 + cc * 8;
            bf16x8 v8 = *(const bf16x8*)&qkv[((size_t)b * 4096 + n) * 512 + 256 + k];
            f32x4 a0 = *(const f32x4*)&xr[h * 256 + k];
            f32x4 a1 = *(const f32x4*)&xr[h * 256 + k + 4];
            f32x4 c0 = *(const f32x4*)&xc[ww * 256 + k];
            f32x4 c1 = *(const f32x4*)&xc[ww * 256 + k + 4];
            bf16x8 o;
            o[0] = f2bf(fmaxf(bf2f(v8[0]) + a0[0] + c0[0], 0.f));
            o[1] = f2bf(fmaxf(bf2f(v8[1]) + a0[1] + c0[1], 0.f));
            o[2] = f2bf(fmaxf(bf2f(v8[2]) + a0[2] + c0[2], 0.f));
            o[3] = f2bf(fmaxf(bf2f(v8[3]) + a0[3] + c0[3], 0.f));
            o[4] = f2bf(fmaxf(bf2f(v8[4]) + a1[0] + c1[0], 0.f));
            o[5] = f2bf(fmaxf(bf2f(v8[5]) + a1[1] + c1[1], 0.f));
            o[6] = f2bf(fmaxf(bf2f(v8[6]) + a1[2] + c1[2], 0.f));
            o[7] = f2bf(fmaxf(bf2f(v8[7]) + a1[3] + c1[3], 0.f));
            *(bf16x8*)&sB[r * 128 + swz(r, cc * 8)] = o;
        }
        __syncthreads();
        mfma_tile<128, 2, 2>(sA, sB, acc_pj, lane, arow0, brow0);
    }
    // epilogue: gate, LDS transpose to [co][n], then f32x4 coalesced stores
    __syncthreads();
    float* sT = (float*)sA;  // [128 co][64 n]
    #pragma unroll
    for (int i = 0; i < 2; ++i)
        #pragma unroll
        for (int r = 0; r < 4; ++r)
            #pragma unroll
            for (int j = 0; j < 2; ++j) {
                int co = arow0 + i * 16 + ((lane >> 4) * 4 + r);
                int n  = brow0 + j * 16 + (lane & 15);
                float p = acc_pj[i][j][r] + bias_proj[co];
                float hs = fminf(fmaxf(p + 3.f, 0.f), 6.f) * (1.f / 6.f);
                sT[co * 64 + n] = hs * (acc_pw[i][j][r] + bias_pw[co]);
            }
    __syncthreads();
    #pragma unroll
    for (int u = 0; u < 4; ++u) {            // 2048 f32x4 units over 512 threads
        int unit = t + u * 512;
        int co = unit >> 4, n4 = (unit & 15) * 4;
        f32x4 v = *(const f32x4*)&sT[co * 64 + n4];
        *(f32x4*)&out[((size_t)b * 128 + co) * 4096 + nt * 64 + n4] = v;
    }
}

// ---------- workspace layout (bytes) ----------
static constexpr size_t OFF_WF_QKV = 0;                        // 131072
static constexpr size_t OFF_WPW    = 131072;                   // 131072
static constexpr size_t OFF_WPROJ  = 262144;                   // 65536
static constexpr size_t OFF_WRC    = 327680;                   // 262144 (bf16 [2][256][256])
static constexpr size_t OFF_WDW    = 589824;                   // wdw_t[9][512] f32 (padded)
static constexpr size_t OFF_BQKV   = 610304;
static constexpr size_t OFF_BDW    = 612352;
static constexpr size_t OFF_BPW    = 614400;
static constexpr size_t OFF_BROW   = 615424;
static constexpr size_t OFF_BCOL   = 616448;
static constexpr size_t OFF_BPROJ  = 617472;
static constexpr size_t OFF_XMEANT = 17395712;                 // 1048576
static constexpr size_t OFF_QM     = 18444288;                 // 4194304
static constexpr size_t OFF_ATTNT  = 22638592;                 // 1048576 (bf16)
static constexpr size_t OFF_XRC    = 23687168;                 // 2097152
static constexpr size_t OFF_QKV    = 25784320;                 // 67108864
static constexpr size_t OFF_DWOUT  = 92893184;                 // 67108864

extern "C" void kernel_launch(void* const* d_in, const int* in_sizes, int n_in,
                              void* d_out, int out_size, void* d_ws, size_t ws_size,
                              hipStream_t stream) {
    const float* x     = (const float*)d_in[0];
    const float* wq    = (const float*)d_in[1];
    const float* sq    = (const float*)d_in[2];
    const float* bq    = (const float*)d_in[3];
    const float* wk    = (const float*)d_in[4];
    const float* sk    = (const float*)d_in[5];
    const float* bk    = (const float*)d_in[6];
    const float* wv    = (const float*)d_in[7];
    const float* sv    = (const float*)d_in[8];
    const float* bv    = (const float*)d_in[9];
    const float* wdw   = (const float*)d_in[10];
    const float* sdw   = (const float*)d_in[11];
    const float* bdw   = (const float*)d_in[12];
    const float* wpw   = (const float*)d_in[13];
    const float* spw   = (const float*)d_in[14];
    const float* bpw   = (const float*)d_in[15];
    const float* wrow  = (const float*)d_in[16];
    const float* srow  = (const float*)d_in[17];
    const float* brow  = (const float*)d_in[18];
    const float* wcol  = (const float*)d_in[19];
    const float* scol  = (const float*)d_in[20];
    const float* bcol  = (const float*)d_in[21];
    const float* wproj = (const float*)d_in[22];
    const float* sproj = (const float*)d_in[23];
    const float* bproj = (const float*)d_in[24];
    const float* pe_rq = (const float*)d_in[25];
    const float* pe_rk = (const float*)d_in[26];
    const float* pe_cq = (const float*)d_in[27];
    const float* pe_ck = (const float*)d_in[28];

    char* ws = (char*)d_ws;
    __bf16* wf_qkv   = (__bf16*)(ws + OFF_WF_QKV);
    __bf16* wpw_f    = (__bf16*)(ws + OFF_WPW);
    __bf16* wproj_f  = (__bf16*)(ws + OFF_WPROJ);
    __bf16* wrc_f    = (__bf16*)(ws + OFF_WRC);
    float* wdw_t     = (float*)(ws + OFF_WDW);
    float* bias_qkv  = (float*)(ws + OFF_BQKV);
    float* bias_dw   = (float*)(ws + OFF_BDW);
    float* bias_pw   = (float*)(ws + OFF_BPW);
    float* bias_row  = (float*)(ws + OFF_BROW);
    float* bias_col  = (float*)(ws + OFF_BCOL);
    float* bias_proj = (float*)(ws + OFF_BPROJ);
    float* xmT       = (float*)(ws + OFF_XMEANT);
    float* qm        = (float*)(ws + OFF_QM);
    __bf16* attnT    = (__bf16*)(ws + OFF_ATTNT);
    float* xrc       = (float*)(ws + OFF_XRC);
    __bf16* qkv      = (__bf16*)(ws + OFF_QKV);
    __bf16* dwout    = (__bf16*)(ws + OFF_DWOUT);

    k0_fold<<<1170, 256, 0, stream>>>(wq, sq, bq, wk, sk, bk, wv, sv, bv,
                                      wdw, sdw, bdw, wpw, spw, bpw,
                                      wrow, srow, brow, wcol, scol, bcol,
                                      wproj, sproj, bproj,
                                      wf_qkv, bias_qkv, wdw_t, bias_dw, wpw_f, bias_pw,
                                      wrc_f, bias_row, bias_col, wproj_f, bias_proj);
    kM_xmean<<<dim3(16, 32), 256, 0, stream>>>(x, xmT);
    kQM<<<dim3(16, 2, 4), 256, 0, stream>>>(wf_qkv, bias_qkv, xmT, qm);
    k3_attn<<<dim3(16, 2, 8), 64, 0, stream>>>(qm, pe_rq, pe_rk, pe_cq, pe_ck, attnT);
    k4_rcconv<<<dim3(16, 2, 2), 256, 0, stream>>>(attnT, wrc_f, bias_row, bias_col, xrc);
    k1_qkv<<<dim3(16, 32), 256, 0, stream>>>(x, wf_qkv, bias_qkv, qkv);
    k5_dw<<<dim3(16, 16, 16), 256, 0, stream>>>(qkv, wdw_t, bias_dw, dwout);
    k67_fused<<<1024, 512, 0, stream>>>(dwout, wpw_f, bias_pw, qkv, wproj_f,
                                        bias_proj, xrc, (float*)d_out);
}

// Round 19
// 142.581 us; speedup vs baseline: 1.0079x; 1.0079x over previous
//
#include <hip/hip_runtime.h>
#include <hip/hip_bf16.h>

#define DEV static __device__ __forceinline__

typedef __bf16 bf16x8 __attribute__((ext_vector_type(8)));
typedef __bf16 bf16x4 __attribute__((ext_vector_type(4)));
typedef float  f32x4  __attribute__((ext_vector_type(4)));

// B=16, C=128, H=W=64, HW=4096. qkv channels: q 0..127, k 128..255, v 256..511

// Hand-rolled conversions: measured faster than native (__bf16) casts (R6 regression:
// k67 40.8 -> 58.9 us with native casts; integer RNE restores it).
DEV float bf2f(__bf16 b) {
    unsigned short h = __builtin_bit_cast(unsigned short, b);
    unsigned int u = ((unsigned int)h) << 16;
    return __builtin_bit_cast(float, u);
}
DEV __bf16 f2bf(float f) {
    unsigned int u = __builtin_bit_cast(unsigned int, f);
    unsigned int r = (u + 0x7fffu + ((u >> 16) & 1u)) >> 16;
    unsigned short h = (unsigned short)r;
    return __builtin_bit_cast(__bf16, h);
}
DEV __bf16 bf_zero() { return __builtin_bit_cast(__bf16, (unsigned short)0); }

// XOR swizzle (elements): k ^= (row&7)<<3  (== byte ^ ((row&7)<<4); slot ^= row&7 in 16B units)
DEV int swz(int row, int k) { return k ^ ((row & 7) << 3); }

// async global->LDS, 16B per lane; LDS dest = uniform base + lane*16 (linear 1KB/wave-issue)
DEV void gload_lds16(const void* g, void* l) {
    __builtin_amdgcn_global_load_lds((const __attribute__((address_space(1))) unsigned int*)g,
                                     (__attribute__((address_space(3))) unsigned int*)l, 16, 0, 0);
}

// MFMA tile: sA rows -> out rows ((lane>>4)*4+r), sB rows -> out cols (lane&15)
template <int RK, int MREP, int NREP>
DEV void mfma_tile(const __bf16* sA, const __bf16* sB, f32x4 (&acc)[MREP][NREP],
                   int lane, int arow0, int brow0) {
    #pragma unroll
    for (int kk = 0; kk < RK; kk += 32) {
        const int krow = kk + ((lane >> 4) << 3);
        bf16x8 a[MREP], b[NREP];
        #pragma unroll
        for (int i = 0; i < MREP; ++i) {
            const int ra = arow0 + i * 16 + (lane & 15);
            a[i] = *(const bf16x8*)&sA[ra * RK + swz(ra, krow)];
        }
        #pragma unroll
        for (int j = 0; j < NREP; ++j) {
            const int rb = brow0 + j * 16 + (lane & 15);
            b[j] = *(const bf16x8*)&sB[rb * RK + swz(rb, krow)];
        }
        #pragma unroll
        for (int i = 0; i < MREP; ++i)
            #pragma unroll
            for (int j = 0; j < NREP; ++j)
                acc[i][j] = __builtin_amdgcn_mfma_f32_16x16x32_bf16(a[i], b[j], acc[i][j], 0, 0, 0);
    }
}

// ---------- K0: fold BN scales into weights ----------
__global__ __launch_bounds__(256) void k0_fold(
    const float* __restrict__ wq, const float* __restrict__ sq, const float* __restrict__ bq,
    const float* __restrict__ wk, const float* __restrict__ sk, const float* __restrict__ bk,
    const float* __restrict__ wv, const float* __restrict__ sv, const float* __restrict__ bv,
    const float* __restrict__ wdw, const float* __restrict__ sdw, const float* __restrict__ bdw,
    const float* __restrict__ wpw, const float* __restrict__ spw, const float* __restrict__ bpw,
    const float* __restrict__ wrow, const float* __restrict__ srow, const float* __restrict__ brow,
    const float* __restrict__ wcol, const float* __restrict__ scol, const float* __restrict__ bcol,
    const float* __restrict__ wproj, const float* __restrict__ sproj, const float* __restrict__ bproj,
    __bf16* __restrict__ wf_qkv, float* __restrict__ bias_qkv,
    float* __restrict__ wdw_t, float* __restrict__ bias_dw,
    __bf16* __restrict__ wpw_f, float* __restrict__ bias_pw,
    __bf16* __restrict__ wrc, float* __restrict__ bias_row, float* __restrict__ bias_col,
    __bf16* __restrict__ wproj_f, float* __restrict__ bias_proj) {
    int id = blockIdx.x * 256 + threadIdx.x;
    if (id < 65536) {  // qkv weights [512][128]
        int co = id >> 7, ci = id & 127;
        float w, s, b;
        if (co < 128)      { w = wq[co * 128 + ci];        s = sq[co];        b = bq[co]; }
        else if (co < 256) { int c = co - 128; w = wk[c * 128 + ci]; s = sk[c]; b = bk[c]; }
        else               { int c = co - 256; w = wv[c * 128 + ci]; s = sv[c]; b = bv[c]; }
        wf_qkv[id] = f2bf(w * s);
        if (ci == 0) bias_qkv[co] = b;
        return;
    }
    id -= 65536;
    if (id < 4608) {  // dw [512][9] -> tap-major wdw_t[9][512]
        int c = id / 9, tap = id - c * 9;
        wdw_t[tap * 512 + c] = wdw[id] * sdw[c];
        if (tap == 0) bias_dw[c] = bdw[c];
        return;
    }
    id -= 4608;
    if (id < 65536) {  // pw [128][512]
        int co = id >> 9;
        wpw_f[id] = f2bf(wpw[id] * spw[co]);
        if ((id & 511) == 0) bias_pw[co] = bpw[co];
        return;
    }
    id -= 65536;
    if (id < 65536) {  // row [256][256] -> wrc[0]
        int co = id >> 8;
        wrc[id] = f2bf(wrow[id] * srow[co]);
        if ((id & 255) == 0) bias_row[co] = brow[co];
        return;
    }
    id -= 65536;
    if (id < 65536) {  // col [256][256] -> wrc[1]
        int co = id >> 8;
        wrc[65536 + id] = f2bf(wcol[id] * scol[co]);
        if ((id & 255) == 0) bias_col[co] = bcol[co];
        return;
    }
    id -= 65536;
    if (id < 32768) {  // proj [128][256]
        int co = id >> 8;
        wproj_f[id] = f2bf(wproj[id] * sproj[co]);
        if ((id & 255) == 0) bias_proj[co] = bproj[co];
        return;
    }
}

// ---------- KM: x row/col means, single coalesced pass -> xmT [b][2][64 pos][128 ci] ----------
__global__ __launch_bounds__(256) void kM_xmean(const float* __restrict__ x,
                                                float* __restrict__ xmT) {
    const int b = blockIdx.x;
    const int wv = threadIdx.x >> 6, lane = threadIdx.x & 63;
    const int c = blockIdx.y * 4 + wv;
    __shared__ float sRow[4][64];
    __shared__ float sCol[4][64];
    const float* p = x + ((size_t)b * 128 + c) * 4096;
    float cacc0 = 0.f, cacc1 = 0.f, cacc2 = 0.f, cacc3 = 0.f;
    #pragma unroll
    for (int g = 0; g < 16; ++g) {
        f32x4 v = *(const f32x4*)&p[(g * 64 + lane) * 4];
        cacc0 += v[0]; cacc1 += v[1]; cacc2 += v[2]; cacc3 += v[3];
        float s = v[0] + v[1] + v[2] + v[3];
        s += __shfl_xor(s, 1);
        s += __shfl_xor(s, 2);
        s += __shfl_xor(s, 4);
        s += __shfl_xor(s, 8);
        if ((lane & 15) == 0) sRow[wv][g * 4 + (lane >> 4)] = s;
    }
    cacc0 += __shfl_xor(cacc0, 16); cacc0 += __shfl_xor(cacc0, 32);
    cacc1 += __shfl_xor(cacc1, 16); cacc1 += __shfl_xor(cacc1, 32);
    cacc2 += __shfl_xor(cacc2, 16); cacc2 += __shfl_xor(cacc2, 32);
    cacc3 += __shfl_xor(cacc3, 16); cacc3 += __shfl_xor(cacc3, 32);
    if (lane < 16) {
        sCol[wv][lane * 4]     = cacc0;
        sCol[wv][lane * 4 + 1] = cacc1;
        sCol[wv][lane * 4 + 2] = cacc2;
        sCol[wv][lane * 4 + 3] = cacc3;
    }
    __syncthreads();
    xmT[((size_t)(b * 2 + 0) * 64 + lane) * 128 + c] = sRow[wv][lane] * (1.f / 64.f);
    xmT[((size_t)(b * 2 + 1) * 64 + lane) * 128 + c] = sCol[wv][lane] * (1.f / 64.f);
}

// ---------- KQM: qkv means = wf_qkv @ xmean + bias -> qm [b][2][512][64] f32 ----------
__global__ __launch_bounds__(256) void kQM(const __bf16* __restrict__ wf,
                                           const float* __restrict__ bias,
                                           const float* __restrict__ xmT,
                                           float* __restrict__ qm) {
    const int b = blockIdx.x, axis = blockIdx.y, cot = blockIdx.z;
    __shared__ __bf16 sA[128 * 128];
    __shared__ __bf16 sB[64 * 128];
    const int t = threadIdx.x, lane = t & 63, wave = t >> 6;
    #pragma unroll
    for (int u = 0; u < 8; ++u) {
        int unit = t + u * 256; int cc = unit & 15, r = unit >> 4;
        *(bf16x8*)&sA[r * 128 + swz(r, cc * 8)] =
            *(const bf16x8*)&wf[(size_t)(cot * 128 + r) * 128 + cc * 8];
    }
    const float* xb = xmT + (size_t)(b * 2 + axis) * 64 * 128;
    #pragma unroll
    for (int u = 0; u < 4; ++u) {
        int unit = t + u * 256; int cc = unit & 15, r = unit >> 4;
        f32x4 v0 = *(const f32x4*)&xb[r * 128 + cc * 8];
        f32x4 v1 = *(const f32x4*)&xb[r * 128 + cc * 8 + 4];
        bf16x8 o;
        o[0] = f2bf(v0[0]); o[1] = f2bf(v0[1]); o[2] = f2bf(v0[2]); o[3] = f2bf(v0[3]);
        o[4] = f2bf(v1[0]); o[5] = f2bf(v1[1]); o[6] = f2bf(v1[2]); o[7] = f2bf(v1[3]);
        *(bf16x8*)&sB[r * 128 + swz(r, cc * 8)] = o;
    }
    __syncthreads();
    f32x4 acc[4][2];
    #pragma unroll
    for (int i = 0; i < 4; ++i)
        #pragma unroll
        for (int j = 0; j < 2; ++j) acc[i][j] = (f32x4){0.f, 0.f, 0.f, 0.f};
    mfma_tile<128, 4, 2>(sA, sB, acc, lane, (wave & 1) * 64, (wave >> 1) * 32);
    #pragma unroll
    for (int i = 0; i < 4; ++i)
        #pragma unroll
        for (int r = 0; r < 4; ++r)
            #pragma unroll
            for (int j = 0; j < 2; ++j) {
                int c = cot * 128 + (wave & 1) * 64 + i * 16 + ((lane >> 4) * 4 + r);
                int pos = (wave >> 1) * 32 + j * 16 + (lane & 15);
                qm[((size_t)(b * 2 + axis) * 512 + c) * 64 + pos] = acc[i][j][r] + bias[c];
            }
}

// ---------- K3: axial attention -> attnT bf16 [b2][64 pos][256 ci], relu'd ----------
DEV float interp16(const float* __restrict__ p, int i) {
    float c = 0.25f * (float)i - 0.375f;
    c = fminf(fmaxf(c, 0.f), 15.f);
    const int lo = (int)c;
    const int hi = min(lo + 1, 15);
    const float f = c - (float)lo;
    return p[lo] * (1.f - f) + p[hi] * f;
}

__global__ __launch_bounds__(64) void k3_attn(const float* __restrict__ qm,
                                              const float* __restrict__ pe_rq,
                                              const float* __restrict__ pe_rk,
                                              const float* __restrict__ pe_cq,
                                              const float* __restrict__ pe_ck,
                                              __bf16* __restrict__ attnT) {
    const int b = blockIdx.x, axis = blockIdx.y, head = blockIdx.z;
    const float* peq = axis ? pe_cq : pe_rq;
    const float* pek = axis ? pe_ck : pe_rk;
    const int lane = threadIdx.x;
    __shared__ float sQ[64][16];
    __shared__ float sK[16][64];
    __shared__ float sV[64][32];
    const float* mb = qm + (size_t)(b * 2 + axis) * 512 * 64;
    #pragma unroll
    for (int kd = 0; kd < 16; ++kd) {
        const int c = head * 16 + kd;
        sQ[lane][kd] = mb[c * 64 + lane] + interp16(peq + c * 16, lane);
        sK[kd][lane] = mb[(128 + c) * 64 + lane] + interp16(pek + c * 16, lane);
    }
    #pragma unroll
    for (int d = 0; d < 32; ++d) {
        const int c = 256 + head * 32 + d;
        sV[lane][d] = mb[c * 64 + lane];
    }
    __syncthreads();
    float qr[16];
    #pragma unroll
    for (int kd = 0; kd < 16; ++kd) qr[kd] = sQ[lane][kd];
    float s[64];
    #pragma unroll
    for (int j = 0; j < 64; ++j) {
        float a = 0.f;
        #pragma unroll
        for (int kd = 0; kd < 16; ++kd) a += qr[kd] * sK[kd][j];
        s[j] = a * 0.25f;
    }
    float m = -1e30f;
    #pragma unroll
    for (int j = 0; j < 64; ++j) m = fmaxf(m, s[j]);
    float sum = 0.f;
    #pragma unroll
    for (int j = 0; j < 64; ++j) { s[j] = __expf(s[j] - m); sum += s[j]; }
    const float inv = 1.f / sum;
    float O[32];
    #pragma unroll
    for (int d = 0; d < 32; ++d) O[d] = 0.f;
    #pragma unroll
    for (int j = 0; j < 64; ++j) {
        const float pj = s[j] * inv;
        #pragma unroll
        for (int d = 0; d < 32; ++d) O[d] += pj * sV[j][d];
    }
    __bf16* ob = attnT + ((size_t)(b * 2 + axis) * 64 + lane) * 256 + head * 32;
    #pragma unroll
    for (int d8 = 0; d8 < 4; ++d8) {
        bf16x8 o;
        #pragma unroll
        for (int j = 0; j < 8; ++j) o[j] = f2bf(fmaxf(O[d8 * 8 + j], 0.f));
        *(bf16x8*)&ob[d8 * 8] = o;
    }
}

// ---------- K4: wrow/wcol 1x1 conv via MFMA -> xrc [b][2][64 pos][256 co] f32 ----------
__global__ __launch_bounds__(256) void k4_rcconv(const __bf16* __restrict__ attnT,
                                                 const __bf16* __restrict__ wrc,
                                                 const float* __restrict__ brow,
                                                 const float* __restrict__ bcol,
                                                 float* __restrict__ xrc) {
    const int b = blockIdx.x, axis = blockIdx.y, cot = blockIdx.z;
    __shared__ __bf16 sA[128 * 128];           // 32 KB, reused as f32 sT in epilogue
    __shared__ __bf16 sB[2][64 * 128];         // 32 KB: both K-chunks of attnT tile
    const int t = threadIdx.x, lane = t & 63, wave = t >> 6;
    const float* bias = axis ? bcol : brow;
    const __bf16* src = attnT + (size_t)(b * 2 + axis) * 64 * 256;
    #pragma unroll
    for (int u = 0; u < 8; ++u) {
        int unit = t + u * 256;                // 2048 units
        int cj = unit & 31, r = unit >> 5;     // k = cj*8 in 0..255
        int k = cj * 8, chunk = k >> 7, kin = k & 127;
        *(bf16x8*)&sB[chunk][r * 128 + swz(r, kin)] = *(const bf16x8*)&src[r * 256 + k];
    }
    f32x4 acc[4][2];
    #pragma unroll
    for (int i = 0; i < 4; ++i)
        #pragma unroll
        for (int j = 0; j < 2; ++j) acc[i][j] = (f32x4){0.f, 0.f, 0.f, 0.f};
    for (int kc = 0; kc < 2; ++kc) {
        __syncthreads();
        #pragma unroll
        for (int u = 0; u < 8; ++u) {
            int unit = t + u * 256; int cc = unit & 15, r = unit >> 4;
            *(bf16x8*)&sA[r * 128 + swz(r, cc * 8)] =
                *(const bf16x8*)&wrc[(size_t)(axis * 256 + cot * 128 + r) * 256 + kc * 128 + cc * 8];
        }
        __syncthreads();
        mfma_tile<128, 4, 2>(sA, sB[kc], acc, lane, (wave & 1) * 64, (wave >> 1) * 32);
    }
    __syncthreads();
    float* sT = (float*)sA;  // [64 pos][128 co'], co' XOR-swizzled by (pos&7)<<2
    #pragma unroll
    for (int i = 0; i < 4; ++i)
        #pragma unroll
        for (int r = 0; r < 4; ++r)
            #pragma unroll
            for (int j = 0; j < 2; ++j) {
                int cop = (wave & 1) * 64 + i * 16 + ((lane >> 4) * 4 + r);
                int pos = (wave >> 1) * 32 + j * 16 + (lane & 15);
                sT[pos * 128 + (cop ^ ((pos & 7) << 2))] = acc[i][j][r] + bias[cot * 128 + cop];
            }
    __syncthreads();
    #pragma unroll
    for (int u = 0; u < 8; ++u) {
        int unit = t + u * 256;                // 2048 f32x4 units
        int q = unit & 31, pos = unit >> 5;
        f32x4 v = *(const f32x4*)&sT[pos * 128 + ((q * 4) ^ ((pos & 7) << 2))];
        *(f32x4*)&xrc[((size_t)(b * 2 + axis) * 64 + pos) * 256 + cot * 128 + q * 4] = v;
    }
}

// ---------- K1: qkv GEMM reading x directly (kT fused in) -> qkv [b][4096 n][512 co] ----------
__global__ __launch_bounds__(256) void k1_qkv(const float* __restrict__ x,
                                              const __bf16* __restrict__ wf,
                                              const float* __restrict__ bias,
                                              __bf16* __restrict__ qkv) {
    const int b = blockIdx.x, nt = blockIdx.y;
    __shared__ __bf16 sA[128 * 128];  // stage-0: [ci][n] n-swizzled; then weights; then sT
    __shared__ __bf16 sB[128 * 128];  // x tile transposed [n][ci] (staged once)
    const int t = threadIdx.x, lane = t & 63, wave = t >> 6;
    const int n0 = nt * 128;
    const float* xb = x + (size_t)b * 128 * 4096;
    // phase 0a: coalesced f32 read of x[ci][n0+n] -> sA[ci][n] (n XOR-swizzled by (ci>>3)&7)
    #pragma unroll
    for (int u = 0; u < 16; ++u) {
        int unit = t + u * 256;
        int ci = unit >> 5, n4 = (unit & 31) * 4;
        f32x4 v = *(const f32x4*)&xb[(size_t)ci * 4096 + n0 + n4];
        bf16x4 e;
        e[0] = f2bf(v[0]); e[1] = f2bf(v[1]); e[2] = f2bf(v[2]); e[3] = f2bf(v[3]);
        *(bf16x4*)&sA[ci * 128 + (n4 ^ (((ci >> 3) & 7) << 3))] = e;
    }
    __syncthreads();
    // phase 0b: transpose into sB[n][ci] (ci XOR-swizzled by swz(n,..))
    #pragma unroll
    for (int u = 0; u < 8; ++u) {
        int unit = t + u * 256;
        int cg = unit & 15, n = unit >> 4;
        bf16x8 o;
        #pragma unroll
        for (int j = 0; j < 8; ++j) {
            int ci = cg * 8 + j;
            o[j] = sA[ci * 128 + (n ^ (((ci >> 3) & 7) << 3))];
        }
        *(bf16x8*)&sB[n * 128 + swz(n, cg * 8)] = o;
    }
    for (int cot = 0; cot < 4; ++cot) {
        __syncthreads();
        #pragma unroll
        for (int u = 0; u < 8; ++u) {
            int unit = t + u * 256; int cc = unit & 15, r = unit >> 4;
            *(bf16x8*)&sA[r * 128 + swz(r, cc * 8)] =
                *(const bf16x8*)&wf[(size_t)(cot * 128 + r) * 128 + cc * 8];
        }
        __syncthreads();
        f32x4 acc[4][4];
        #pragma unroll
        for (int i = 0; i < 4; ++i)
            #pragma unroll
            for (int j = 0; j < 4; ++j) acc[i][j] = (f32x4){0.f, 0.f, 0.f, 0.f};
        mfma_tile<128, 4, 4>(sA, sB, acc, lane, (wave >> 1) * 64, (wave & 1) * 64);
        __syncthreads();
        __bf16* sT = sA;  // [n][128 co], co XOR-swizzled by (n&7)<<3
        #pragma unroll
        for (int i = 0; i < 4; ++i)
            #pragma unroll
            for (int r = 0; r < 4; ++r)
                #pragma unroll
                for (int j = 0; j < 4; ++j) {
                    int co = (wave >> 1) * 64 + i * 16 + ((lane >> 4) * 4 + r);
                    int n  = (wave & 1) * 64 + j * 16 + (lane & 15);
                    sT[n * 128 + (co ^ ((n & 7) << 3))] = f2bf(acc[i][j][r] + bias[cot * 128 + co]);
                }
        __syncthreads();
        #pragma unroll
        for (int u = 0; u < 8; ++u) {
            int unit = t + u * 256; int cc = unit & 15, n = unit >> 4;
            bf16x8 vv = *(bf16x8*)&sT[n * 128 + ((cc * 8) ^ ((n & 7) << 3))];
            *(bf16x8*)&qkv[((size_t)b * 4096 + n0 + n) * 512 + cot * 128 + cc * 8] = vv;
        }
    }
}

// ---------- K5: depthwise 3x3 + BN + relu, bf16 LDS + register row-reuse ----------
__global__ __launch_bounds__(256) void k5_dw(const __bf16* __restrict__ qkv,
                                             const float* __restrict__ wdw_t,
                                             const float* __restrict__ bdw,
                                             __bf16* __restrict__ dwo) {
    const int b = blockIdx.x, h0 = blockIdx.y * 4, cs = blockIdx.z * 32;
    __shared__ __bf16 sH[6][66][32];  // 25.3 KB
    const int t = threadIdx.x;
    const int w = t >> 2, cg = t & 3;  // cg: group of 8 channels
    #pragma unroll
    for (int row = 0; row < 6; ++row) {
        int h = h0 + row - 1;
        bf16x8 v;
        #pragma unroll
        for (int j = 0; j < 8; ++j) v[j] = bf_zero();
        if (h >= 0 && h < 64)
            v = *(const bf16x8*)&qkv[((size_t)b * 4096 + h * 64 + w) * 512 + cs + cg * 8];
        *(bf16x8*)&sH[row][w + 1][cg * 8] = v;
    }
    if (t < 192) {  // zero halo columns wz=0 and wz=65
        int row = t >> 5, c = t & 31;
        sH[row][0][c] = bf_zero();
        sH[row][65][c] = bf_zero();
    }
    float acc[4][8];
    {
        float bb[8];
        #pragma unroll
        for (int j = 0; j < 8; ++j) bb[j] = bdw[cs + cg * 8 + j];
        #pragma unroll
        for (int h = 0; h < 4; ++h)
            #pragma unroll
            for (int j = 0; j < 8; ++j) acc[h][j] = bb[j];
    }
    __syncthreads();
    #pragma unroll
    for (int dx = 0; dx < 3; ++dx) {
        f32x4 w0[3], w1[3];
        #pragma unroll
        for (int dy = 0; dy < 3; ++dy) {
            const float* wp = &wdw_t[(dy * 3 + dx) * 512 + cs + cg * 8];
            w0[dy] = *(const f32x4*)wp;
            w1[dy] = *(const f32x4*)(wp + 4);
        }
        float r[6][8];
        #pragma unroll
        for (int row = 0; row < 6; ++row) {
            bf16x8 v = *(const bf16x8*)&sH[row][w + dx][cg * 8];
            #pragma unroll
            for (int j = 0; j < 8; ++j) r[row][j] = bf2f(v[j]);
        }
        #pragma unroll
        for (int h = 0; h < 4; ++h)
            #pragma unroll
            for (int dy = 0; dy < 3; ++dy) {
                #pragma unroll
                for (int j = 0; j < 4; ++j) {
                    acc[h][j]     += w0[dy][j] * r[h + dy][j];
                    acc[h][4 + j] += w1[dy][j] * r[h + dy][4 + j];
                }
            }
    }
    #pragma unroll
    for (int h = 0; h < 4; ++h) {
        bf16x8 o;
        #pragma unroll
        for (int j = 0; j < 8; ++j) o[j] = f2bf(fmaxf(acc[h][j], 0.f));
        *(bf16x8*)&dwo[((size_t)b * 4096 + (h0 + h) * 64 + w) * 512 + cs + cg * 8] = o;
    }
}

// ---------- K67: fused pw GEMM + proj GEMM + gate; 512 thr, linear grid, vec epilogue ----------
__global__ __launch_bounds__(512) void k67_fused(const __bf16* __restrict__ dws,
                                                 const __bf16* __restrict__ wpw,
                                                 const float* __restrict__ bias_pw,
                                                 const __bf16* __restrict__ qkv,
                                                 const __bf16* __restrict__ wproj,
                                                 const float* __restrict__ bias_proj,
                                                 const float* __restrict__ xrc,
                                                 float* __restrict__ out) {
    const int b = blockIdx.x, nt = blockIdx.y;   // nt = h row (64 pixels)
    __shared__ __bf16 sA[128 * 128];
    __shared__ __bf16 sB[64 * 128];
    const int t = threadIdx.x, lane = t & 63, wave = t >> 6;   // 8 waves
    const int arow0 = (wave & 3) * 32, brow0 = (wave >> 2) * 32;  // 4x2 quadrants of 32x32
    const float* xr = xrc + (size_t)(b * 2 + 0) * 64 * 256;
    const float* xc = xrc + (size_t)(b * 2 + 1) * 64 * 256;
    f32x4 acc_pw[2][2], acc_pj[2][2];
    #pragma unroll
    for (int i = 0; i < 2; ++i)
        #pragma unroll
        for (int j = 0; j < 2; ++j) {
            acc_pw[i][j] = (f32x4){0.f, 0.f, 0.f, 0.f};
            acc_pj[i][j] = (f32x4){0.f, 0.f, 0.f, 0.f};
        }
    // phase 1: pw GEMM, K=512; both operands via async global_load_lds (pre-swizzled src)
    for (int kc = 0; kc < 4; ++kc) {
        __syncthreads();
        #pragma unroll
        for (int u = 0; u < 4; ++u) {          // sA: 32 chunks of 1KB over 8 waves
            int r0 = (wave * 4 + u) * 4;
            int row = r0 + (lane >> 4);
            int slot = (lane & 15) ^ (row & 7);
            gload_lds16(&wpw[(size_t)row * 512 + kc * 128 + slot * 8], &sA[r0 * 128]);
        }
        #pragma unroll
        for (int u = 0; u < 2; ++u) {          // sB: 16 chunks of 1KB
            int r0 = (wave * 2 + u) * 4;
            int row = r0 + (lane >> 4);
            int slot = (lane & 15) ^ (row & 7);
            gload_lds16(&dws[((size_t)b * 4096 + nt * 64 + row) * 512 + kc * 128 + slot * 8],
                        &sB[r0 * 128]);
        }
        __syncthreads();
        mfma_tile<128, 2, 2>(sA, sB, acc_pw, lane, arow0, brow0);
    }
    // phase 2: proj GEMM on relu(v + xx_row + xx_col), K=256 (sA async; sB computed)
    for (int kc = 0; kc < 2; ++kc) {
        __syncthreads();
        #pragma unroll
        for (int u = 0; u < 4; ++u) {
            int r0 = (wave * 4 + u) * 4;
            int row = r0 + (lane >> 4);
            int slot = (lane & 15) ^ (row & 7);
            gload_lds16(&wproj[(size_t)row * 256 + kc * 128 + slot * 8], &sA[r0 * 128]);
        }
        #pragma unroll
        for (int u = 0; u < 2; ++u) {          // 1024 units over 512 threads
            int unit = t + u * 512; int cc = unit & 15, r = unit >> 4;
            int n = nt * 64 + r, h = n >> 6, ww = n & 63;
            int k = kc * 128 + cc * 8;
            bf16x8 v8 = *(const bf16x8*)&qkv[((size_t)b * 4096 + n) * 512 + 256 + k];
            f32x4 a0 = *(const f32x4*)&xr[h * 256 + k];
            f32x4 a1 = *(const f32x4*)&xr[h * 256 + k + 4];
            f32x4 c0 = *(const f32x4*)&xc[ww * 256 + k];
            f32x4 c1 = *(const f32x4*)&xc[ww * 256 + k + 4];
            bf16x8 o;
            o[0] = f2bf(fmaxf(bf2f(v8[0]) + a0[0] + c0[0], 0.f));
            o[1] = f2bf(fmaxf(bf2f(v8[1]) + a0[1] + c0[1], 0.f));
            o[2] = f2bf(fmaxf(bf2f(v8[2]) + a0[2] + c0[2], 0.f));
            o[3] = f2bf(fmaxf(bf2f(v8[3]) + a0[3] + c0[3], 0.f));
            o[4] = f2bf(fmaxf(bf2f(v8[4]) + a1[0] + c1[0], 0.f));
            o[5] = f2bf(fmaxf(bf2f(v8[5]) + a1[1] + c1[1], 0.f));
            o[6] = f2bf(fmaxf(bf2f(v8[6]) + a1[2] + c1[2], 0.f));
            o[7] = f2bf(fmaxf(bf2f(v8[7]) + a1[3] + c1[3], 0.f));
            *(bf16x8*)&sB[r * 128 + swz(r, cc * 8)] = o;
        }
        __syncthreads();
        mfma_tile<128, 2, 2>(sA, sB, acc_pj, lane, arow0, brow0);
    }
    // epilogue: gate, LDS transpose to [co][n], then f32x4 coalesced stores
    __syncthreads();
    float* sT = (float*)sA;  // [128 co][64 n]
    #pragma unroll
    for (int i = 0; i < 2; ++i)
        #pragma unroll
        for (int r = 0; r < 4; ++r)
            #pragma unroll
            for (int j = 0; j < 2; ++j) {
                int co = arow0 + i * 16 + ((lane >> 4) * 4 + r);
                int n  = brow0 + j * 16 + (lane & 15);
                float p = acc_pj[i][j][r] + bias_proj[co];
                float hs = fminf(fmaxf(p + 3.f, 0.f), 6.f) * (1.f / 6.f);
                sT[co * 64 + n] = hs * (acc_pw[i][j][r] + bias_pw[co]);
            }
    __syncthreads();
    #pragma unroll
    for (int u = 0; u < 4; ++u) {            // 2048 f32x4 units over 512 threads
        int unit = t + u * 512;
        int co = unit >> 4, n4 = (unit & 15) * 4;
        f32x4 v = *(const f32x4*)&sT[co * 64 + n4];
        *(f32x4*)&out[((size_t)b * 128 + co) * 4096 + nt * 64 + n4] = v;
    }
}

// ---------- workspace layout (bytes) ----------
static constexpr size_t OFF_WF_QKV = 0;                        // 131072
static constexpr size_t OFF_WPW    = 131072;                   // 131072
static constexpr size_t OFF_WPROJ  = 262144;                   // 65536
static constexpr size_t OFF_WRC    = 327680;                   // 262144 (bf16 [2][256][256])
static constexpr size_t OFF_WDW    = 589824;                   // wdw_t[9][512] f32 (padded)
static constexpr size_t OFF_BQKV   = 610304;
static constexpr size_t OFF_BDW    = 612352;
static constexpr size_t OFF_BPW    = 614400;
static constexpr size_t OFF_BROW   = 615424;
static constexpr size_t OFF_BCOL   = 616448;
static constexpr size_t OFF_BPROJ  = 617472;
static constexpr size_t OFF_XMEANT = 17395712;                 // 1048576
static constexpr size_t OFF_QM     = 18444288;                 // 4194304
static constexpr size_t OFF_ATTNT  = 22638592;                 // 1048576 (bf16)
static constexpr size_t OFF_XRC    = 23687168;                 // 2097152
static constexpr size_t OFF_QKV    = 25784320;                 // 67108864
static constexpr size_t OFF_DWOUT  = 92893184;                 // 67108864

extern "C" void kernel_launch(void* const* d_in, const int* in_sizes, int n_in,
                              void* d_out, int out_size, void* d_ws, size_t ws_size,
                              hipStream_t stream) {
    const float* x     = (const float*)d_in[0];
    const float* wq    = (const float*)d_in[1];
    const float* sq    = (const float*)d_in[2];
    const float* bq    = (const float*)d_in[3];
    const float* wk    = (const float*)d_in[4];
    const float* sk    = (const float*)d_in[5];
    const float* bk    = (const float*)d_in[6];
    const float* wv    = (const float*)d_in[7];
    const float* sv    = (const float*)d_in[8];
    const float* bv    = (const float*)d_in[9];
    const float* wdw   = (const float*)d_in[10];
    const float* sdw   = (const float*)d_in[11];
    const float* bdw   = (const float*)d_in[12];
    const float* wpw   = (const float*)d_in[13];
    const float* spw   = (const float*)d_in[14];
    const float* bpw   = (const float*)d_in[15];
    const float* wrow  = (const float*)d_in[16];
    const float* srow  = (const float*)d_in[17];
    const float* brow  = (const float*)d_in[18];
    const float* wcol  = (const float*)d_in[19];
    const float* scol  = (const float*)d_in[20];
    const float* bcol  = (const float*)d_in[21];
    const float* wproj = (const float*)d_in[22];
    const float* sproj = (const float*)d_in[23];
    const float* bproj = (const float*)d_in[24];
    const float* pe_rq = (const float*)d_in[25];
    const float* pe_rk = (const float*)d_in[26];
    const float* pe_cq = (const float*)d_in[27];
    const float* pe_ck = (const float*)d_in[28];

    char* ws = (char*)d_ws;
    __bf16* wf_qkv   = (__bf16*)(ws + OFF_WF_QKV);
    __bf16* wpw_f    = (__bf16*)(ws + OFF_WPW);
    __bf16* wproj_f  = (__bf16*)(ws + OFF_WPROJ);
    __bf16* wrc_f    = (__bf16*)(ws + OFF_WRC);
    float* wdw_t     = (float*)(ws + OFF_WDW);
    float* bias_qkv  = (float*)(ws + OFF_BQKV);
    float* bias_dw   = (float*)(ws + OFF_BDW);
    float* bias_pw   = (float*)(ws + OFF_BPW);
    float* bias_row  = (float*)(ws + OFF_BROW);
    float* bias_col  = (float*)(ws + OFF_BCOL);
    float* bias_proj = (float*)(ws + OFF_BPROJ);
    float* xmT       = (float*)(ws + OFF_XMEANT);
    float* qm        = (float*)(ws + OFF_QM);
    __bf16* attnT    = (__bf16*)(ws + OFF_ATTNT);
    float* xrc       = (float*)(ws + OFF_XRC);
    __bf16* qkv      = (__bf16*)(ws + OFF_QKV);
    __bf16* dwout    = (__bf16*)(ws + OFF_DWOUT);

    k0_fold<<<1170, 256, 0, stream>>>(wq, sq, bq, wk, sk, bk, wv, sv, bv,
                                      wdw, sdw, bdw, wpw, spw, bpw,
                                      wrow, srow, brow, wcol, scol, bcol,
                                      wproj, sproj, bproj,
                                      wf_qkv, bias_qkv, wdw_t, bias_dw, wpw_f, bias_pw,
                                      wrc_f, bias_row, bias_col, wproj_f, bias_proj);
    kM_xmean<<<dim3(16, 32), 256, 0, stream>>>(x, xmT);
    kQM<<<dim3(16, 2, 4), 256, 0, stream>>>(wf_qkv, bias_qkv, xmT, qm);
    k3_attn<<<dim3(16, 2, 8), 64, 0, stream>>>(qm, pe_rq, pe_rk, pe_cq, pe_ck, attnT);
    k4_rcconv<<<dim3(16, 2, 2), 256, 0, stream>>>(attnT, wrc_f, bias_row, bias_col, xrc);
    k1_qkv<<<dim3(16, 32), 256, 0, stream>>>(x, wf_qkv, bias_qkv, qkv);
    k5_dw<<<dim3(16, 16, 16), 256, 0, stream>>>(qkv, wdw_t, bias_dw, dwout);
    k67_fused<<<dim3(16, 64), 512, 0, stream>>>(dwout, wpw_f, bias_pw, qkv, wproj_f,
                                                bias_proj, xrc, (float*)d_out);
}

// Round 20
// 141.493 us; speedup vs baseline: 1.0156x; 1.0077x over previous
//
#include <hip/hip_runtime.h>
#include <hip/hip_bf16.h>

#define DEV static __device__ __forceinline__

typedef __bf16 bf16x8 __attribute__((ext_vector_type(8)));
typedef __bf16 bf16x4 __attribute__((ext_vector_type(4)));
typedef float  f32x4  __attribute__((ext_vector_type(4)));

// B=16, C=128, H=W=64, HW=4096. qkv channels: q 0..127, k 128..255, v 256..511

// Hand-rolled conversions: measured faster than native (__bf16) casts (R6 regression:
// k67 40.8 -> 58.9 us with native casts; integer RNE restores it).
DEV float bf2f(__bf16 b) {
    unsigned short h = __builtin_bit_cast(unsigned short, b);
    unsigned int u = ((unsigned int)h) << 16;
    return __builtin_bit_cast(float, u);
}
DEV __bf16 f2bf(float f) {
    unsigned int u = __builtin_bit_cast(unsigned int, f);
    unsigned int r = (u + 0x7fffu + ((u >> 16) & 1u)) >> 16;
    unsigned short h = (unsigned short)r;
    return __builtin_bit_cast(__bf16, h);
}
DEV __bf16 bf_zero() { return __builtin_bit_cast(__bf16, (unsigned short)0); }

// XOR swizzle (elements): k ^= (row&7)<<3  (== byte ^ ((row&7)<<4); slot ^= row&7 in 16B units)
DEV int swz(int row, int k) { return k ^ ((row & 7) << 3); }

// async global->LDS, 16B per lane; LDS dest = uniform base + lane*16 (linear 1KB/wave-issue)
DEV void gload_lds16(const void* g, void* l) {
    __builtin_amdgcn_global_load_lds((const __attribute__((address_space(1))) unsigned int*)g,
                                     (__attribute__((address_space(3))) unsigned int*)l, 16, 0, 0);
}

// MFMA tile: sA rows -> out rows ((lane>>4)*4+r), sB rows -> out cols (lane&15)
template <int RK, int MREP, int NREP>
DEV void mfma_tile(const __bf16* sA, const __bf16* sB, f32x4 (&acc)[MREP][NREP],
                   int lane, int arow0, int brow0) {
    #pragma unroll
    for (int kk = 0; kk < RK; kk += 32) {
        const int krow = kk + ((lane >> 4) << 3);
        bf16x8 a[MREP], b[NREP];
        #pragma unroll
        for (int i = 0; i < MREP; ++i) {
            const int ra = arow0 + i * 16 + (lane & 15);
            a[i] = *(const bf16x8*)&sA[ra * RK + swz(ra, krow)];
        }
        #pragma unroll
        for (int j = 0; j < NREP; ++j) {
            const int rb = brow0 + j * 16 + (lane & 15);
            b[j] = *(const bf16x8*)&sB[rb * RK + swz(rb, krow)];
        }
        #pragma unroll
        for (int i = 0; i < MREP; ++i)
            #pragma unroll
            for (int j = 0; j < NREP; ++j)
                acc[i][j] = __builtin_amdgcn_mfma_f32_16x16x32_bf16(a[i], b[j], acc[i][j], 0, 0, 0);
    }
}

// ---------- K0: fold BN scales into weights ----------
__global__ __launch_bounds__(256) void k0_fold(
    const float* __restrict__ wq, const float* __restrict__ sq, const float* __restrict__ bq,
    const float* __restrict__ wk, const float* __restrict__ sk, const float* __restrict__ bk,
    const float* __restrict__ wv, const float* __restrict__ sv, const float* __restrict__ bv,
    const float* __restrict__ wdw, const float* __restrict__ sdw, const float* __restrict__ bdw,
    const float* __restrict__ wpw, const float* __restrict__ spw, const float* __restrict__ bpw,
    const float* __restrict__ wrow, const float* __restrict__ srow, const float* __restrict__ brow,
    const float* __restrict__ wcol, const float* __restrict__ scol, const float* __restrict__ bcol,
    const float* __restrict__ wproj, const float* __restrict__ sproj, const float* __restrict__ bproj,
    __bf16* __restrict__ wf_qkv, float* __restrict__ bias_qkv,
    float* __restrict__ wdw_t, float* __restrict__ bias_dw,
    __bf16* __restrict__ wpw_f, float* __restrict__ bias_pw,
    __bf16* __restrict__ wrc, float* __restrict__ bias_row, float* __restrict__ bias_col,
    __bf16* __restrict__ wproj_f, float* __restrict__ bias_proj) {
    int id = blockIdx.x * 256 + threadIdx.x;
    if (id < 65536) {  // qkv weights [512][128]
        int co = id >> 7, ci = id & 127;
        float w, s, b;
        if (co < 128)      { w = wq[co * 128 + ci];        s = sq[co];        b = bq[co]; }
        else if (co < 256) { int c = co - 128; w = wk[c * 128 + ci]; s = sk[c]; b = bk[c]; }
        else               { int c = co - 256; w = wv[c * 128 + ci]; s = sv[c]; b = bv[c]; }
        wf_qkv[id] = f2bf(w * s);
        if (ci == 0) bias_qkv[co] = b;
        return;
    }
    id -= 65536;
    if (id < 4608) {  // dw [512][9] -> tap-major wdw_t[9][512]
        int c = id / 9, tap = id - c * 9;
        wdw_t[tap * 512 + c] = wdw[id] * sdw[c];
        if (tap == 0) bias_dw[c] = bdw[c];
        return;
    }
    id -= 4608;
    if (id < 65536) {  // pw [128][512]
        int co = id >> 9;
        wpw_f[id] = f2bf(wpw[id] * spw[co]);
        if ((id & 511) == 0) bias_pw[co] = bpw[co];
        return;
    }
    id -= 65536;
    if (id < 65536) {  // row [256][256] -> wrc[0]
        int co = id >> 8;
        wrc[id] = f2bf(wrow[id] * srow[co]);
        if ((id & 255) == 0) bias_row[co] = brow[co];
        return;
    }
    id -= 65536;
    if (id < 65536) {  // col [256][256] -> wrc[1]
        int co = id >> 8;
        wrc[65536 + id] = f2bf(wcol[id] * scol[co]);
        if ((id & 255) == 0) bias_col[co] = bcol[co];
        return;
    }
    id -= 65536;
    if (id < 32768) {  // proj [128][256]
        int co = id >> 8;
        wproj_f[id] = f2bf(wproj[id] * sproj[co]);
        if ((id & 255) == 0) bias_proj[co] = bproj[co];
        return;
    }
}

// ---------- KM: x row/col means, single coalesced pass -> xmT [b][2][64 pos][128 ci] ----------
__global__ __launch_bounds__(256) void kM_xmean(const float* __restrict__ x,
                                                float* __restrict__ xmT) {
    const int b = blockIdx.x;
    const int wv = threadIdx.x >> 6, lane = threadIdx.x & 63;
    const int c = blockIdx.y * 4 + wv;
    __shared__ float sRow[4][64];
    __shared__ float sCol[4][64];
    const float* p = x + ((size_t)b * 128 + c) * 4096;
    float cacc0 = 0.f, cacc1 = 0.f, cacc2 = 0.f, cacc3 = 0.f;
    #pragma unroll
    for (int g = 0; g < 16; ++g) {
        f32x4 v = *(const f32x4*)&p[(g * 64 + lane) * 4];
        cacc0 += v[0]; cacc1 += v[1]; cacc2 += v[2]; cacc3 += v[3];
        float s = v[0] + v[1] + v[2] + v[3];
        s += __shfl_xor(s, 1);
        s += __shfl_xor(s, 2);
        s += __shfl_xor(s, 4);
        s += __shfl_xor(s, 8);
        if ((lane & 15) == 0) sRow[wv][g * 4 + (lane >> 4)] = s;
    }
    cacc0 += __shfl_xor(cacc0, 16); cacc0 += __shfl_xor(cacc0, 32);
    cacc1 += __shfl_xor(cacc1, 16); cacc1 += __shfl_xor(cacc1, 32);
    cacc2 += __shfl_xor(cacc2, 16); cacc2 += __shfl_xor(cacc2, 32);
    cacc3 += __shfl_xor(cacc3, 16); cacc3 += __shfl_xor(cacc3, 32);
    if (lane < 16) {
        sCol[wv][lane * 4]     = cacc0;
        sCol[wv][lane * 4 + 1] = cacc1;
        sCol[wv][lane * 4 + 2] = cacc2;
        sCol[wv][lane * 4 + 3] = cacc3;
    }
    __syncthreads();
    xmT[((size_t)(b * 2 + 0) * 64 + lane) * 128 + c] = sRow[wv][lane] * (1.f / 64.f);
    xmT[((size_t)(b * 2 + 1) * 64 + lane) * 128 + c] = sCol[wv][lane] * (1.f / 64.f);
}

// ---------- KQM: qkv means = wf_qkv @ xmean + bias -> qm [b][2][512][64] f32 ----------
__global__ __launch_bounds__(256) void kQM(const __bf16* __restrict__ wf,
                                           const float* __restrict__ bias,
                                           const float* __restrict__ xmT,
                                           float* __restrict__ qm) {
    const int b = blockIdx.x, axis = blockIdx.y, cot = blockIdx.z;
    __shared__ __bf16 sA[128 * 128];
    __shared__ __bf16 sB[64 * 128];
    const int t = threadIdx.x, lane = t & 63, wave = t >> 6;
    #pragma unroll
    for (int u = 0; u < 8; ++u) {
        int unit = t + u * 256; int cc = unit & 15, r = unit >> 4;
        *(bf16x8*)&sA[r * 128 + swz(r, cc * 8)] =
            *(const bf16x8*)&wf[(size_t)(cot * 128 + r) * 128 + cc * 8];
    }
    const float* xb = xmT + (size_t)(b * 2 + axis) * 64 * 128;
    #pragma unroll
    for (int u = 0; u < 4; ++u) {
        int unit = t + u * 256; int cc = unit & 15, r = unit >> 4;
        f32x4 v0 = *(const f32x4*)&xb[r * 128 + cc * 8];
        f32x4 v1 = *(const f32x4*)&xb[r * 128 + cc * 8 + 4];
        bf16x8 o;
        o[0] = f2bf(v0[0]); o[1] = f2bf(v0[1]); o[2] = f2bf(v0[2]); o[3] = f2bf(v0[3]);
        o[4] = f2bf(v1[0]); o[5] = f2bf(v1[1]); o[6] = f2bf(v1[2]); o[7] = f2bf(v1[3]);
        *(bf16x8*)&sB[r * 128 + swz(r, cc * 8)] = o;
    }
    __syncthreads();
    f32x4 acc[4][2];
    #pragma unroll
    for (int i = 0; i < 4; ++i)
        #pragma unroll
        for (int j = 0; j < 2; ++j) acc[i][j] = (f32x4){0.f, 0.f, 0.f, 0.f};
    mfma_tile<128, 4, 2>(sA, sB, acc, lane, (wave & 1) * 64, (wave >> 1) * 32);
    #pragma unroll
    for (int i = 0; i < 4; ++i)
        #pragma unroll
        for (int r = 0; r < 4; ++r)
            #pragma unroll
            for (int j = 0; j < 2; ++j) {
                int c = cot * 128 + (wave & 1) * 64 + i * 16 + ((lane >> 4) * 4 + r);
                int pos = (wave >> 1) * 32 + j * 16 + (lane & 15);
                qm[((size_t)(b * 2 + axis) * 512 + c) * 64 + pos] = acc[i][j][r] + bias[c];
            }
}

// ---------- K3: axial attention -> attnT bf16 [b2][64 pos][256 ci], relu'd ----------
DEV float interp16(const float* __restrict__ p, int i) {
    float c = 0.25f * (float)i - 0.375f;
    c = fminf(fmaxf(c, 0.f), 15.f);
    const int lo = (int)c;
    const int hi = min(lo + 1, 15);
    const float f = c - (float)lo;
    return p[lo] * (1.f - f) + p[hi] * f;
}

__global__ __launch_bounds__(64) void k3_attn(const float* __restrict__ qm,
                                              const float* __restrict__ pe_rq,
                                              const float* __restrict__ pe_rk,
                                              const float* __restrict__ pe_cq,
                                              const float* __restrict__ pe_ck,
                                              __bf16* __restrict__ attnT) {
    const int b = blockIdx.x, axis = blockIdx.y, head = blockIdx.z;
    const float* peq = axis ? pe_cq : pe_rq;
    const float* pek = axis ? pe_ck : pe_rk;
    const int lane = threadIdx.x;
    __shared__ float sQ[64][16];
    __shared__ float sK[16][64];
    __shared__ float sV[64][32];
    const float* mb = qm + (size_t)(b * 2 + axis) * 512 * 64;
    #pragma unroll
    for (int kd = 0; kd < 16; ++kd) {
        const int c = head * 16 + kd;
        sQ[lane][kd] = mb[c * 64 + lane] + interp16(peq + c * 16, lane);
        sK[kd][lane] = mb[(128 + c) * 64 + lane] + interp16(pek + c * 16, lane);
    }
    #pragma unroll
    for (int d = 0; d < 32; ++d) {
        const int c = 256 + head * 32 + d;
        sV[lane][d] = mb[c * 64 + lane];
    }
    __syncthreads();
    float qr[16];
    #pragma unroll
    for (int kd = 0; kd < 16; ++kd) qr[kd] = sQ[lane][kd];
    float s[64];
    #pragma unroll
    for (int j = 0; j < 64; ++j) {
        float a = 0.f;
        #pragma unroll
        for (int kd = 0; kd < 16; ++kd) a += qr[kd] * sK[kd][j];
        s[j] = a * 0.25f;
    }
    float m = -1e30f;
    #pragma unroll
    for (int j = 0; j < 64; ++j) m = fmaxf(m, s[j]);
    float sum = 0.f;
    #pragma unroll
    for (int j = 0; j < 64; ++j) { s[j] = __expf(s[j] - m); sum += s[j]; }
    const float inv = 1.f / sum;
    float O[32];
    #pragma unroll
    for (int d = 0; d < 32; ++d) O[d] = 0.f;
    #pragma unroll
    for (int j = 0; j < 64; ++j) {
        const float pj = s[j] * inv;
        #pragma unroll
        for (int d = 0; d < 32; ++d) O[d] += pj * sV[j][d];
    }
    __bf16* ob = attnT + ((size_t)(b * 2 + axis) * 64 + lane) * 256 + head * 32;
    #pragma unroll
    for (int d8 = 0; d8 < 4; ++d8) {
        bf16x8 o;
        #pragma unroll
        for (int j = 0; j < 8; ++j) o[j] = f2bf(fmaxf(O[d8 * 8 + j], 0.f));
        *(bf16x8*)&ob[d8 * 8] = o;
    }
}

// ---------- K4: wrow/wcol 1x1 conv via MFMA -> xrc [b][2][64 pos][256 co] f32 ----------
__global__ __launch_bounds__(256) void k4_rcconv(const __bf16* __restrict__ attnT,
                                                 const __bf16* __restrict__ wrc,
                                                 const float* __restrict__ brow,
                                                 const float* __restrict__ bcol,
                                                 float* __restrict__ xrc) {
    const int b = blockIdx.x, axis = blockIdx.y, cot = blockIdx.z;
    __shared__ __bf16 sA[128 * 128];           // 32 KB, reused as f32 sT in epilogue
    __shared__ __bf16 sB[2][64 * 128];         // 32 KB: both K-chunks of attnT tile
    const int t = threadIdx.x, lane = t & 63, wave = t >> 6;
    const float* bias = axis ? bcol : brow;
    const __bf16* src = attnT + (size_t)(b * 2 + axis) * 64 * 256;
    #pragma unroll
    for (int u = 0; u < 8; ++u) {
        int unit = t + u * 256;                // 2048 units
        int cj = unit & 31, r = unit >> 5;     // k = cj*8 in 0..255
        int k = cj * 8, chunk = k >> 7, kin = k & 127;
        *(bf16x8*)&sB[chunk][r * 128 + swz(r, kin)] = *(const bf16x8*)&src[r * 256 + k];
    }
    f32x4 acc[4][2];
    #pragma unroll
    for (int i = 0; i < 4; ++i)
        #pragma unroll
        for (int j = 0; j < 2; ++j) acc[i][j] = (f32x4){0.f, 0.f, 0.f, 0.f};
    for (int kc = 0; kc < 2; ++kc) {
        __syncthreads();
        #pragma unroll
        for (int u = 0; u < 8; ++u) {
            int unit = t + u * 256; int cc = unit & 15, r = unit >> 4;
            *(bf16x8*)&sA[r * 128 + swz(r, cc * 8)] =
                *(const bf16x8*)&wrc[(size_t)(axis * 256 + cot * 128 + r) * 256 + kc * 128 + cc * 8];
        }
        __syncthreads();
        mfma_tile<128, 4, 2>(sA, sB[kc], acc, lane, (wave & 1) * 64, (wave >> 1) * 32);
    }
    __syncthreads();
    float* sT = (float*)sA;  // [64 pos][128 co'], co' XOR-swizzled by (pos&7)<<2
    #pragma unroll
    for (int i = 0; i < 4; ++i)
        #pragma unroll
        for (int r = 0; r < 4; ++r)
            #pragma unroll
            for (int j = 0; j < 2; ++j) {
                int cop = (wave & 1) * 64 + i * 16 + ((lane >> 4) * 4 + r);
                int pos = (wave >> 1) * 32 + j * 16 + (lane & 15);
                sT[pos * 128 + (cop ^ ((pos & 7) << 2))] = acc[i][j][r] + bias[cot * 128 + cop];
            }
    __syncthreads();
    #pragma unroll
    for (int u = 0; u < 8; ++u) {
        int unit = t + u * 256;                // 2048 f32x4 units
        int q = unit & 31, pos = unit >> 5;
        f32x4 v = *(const f32x4*)&sT[pos * 128 + ((q * 4) ^ ((pos & 7) << 2))];
        *(f32x4*)&xrc[((size_t)(b * 2 + axis) * 64 + pos) * 256 + cot * 128 + q * 4] = v;
    }
}

// ---------- K1: qkv GEMM reading x directly (kT fused in) -> qkv [b][4096 n][512 co] ----------
__global__ __launch_bounds__(256) void k1_qkv(const float* __restrict__ x,
                                              const __bf16* __restrict__ wf,
                                              const float* __restrict__ bias,
                                              __bf16* __restrict__ qkv) {
    const int b = blockIdx.x, nt = blockIdx.y;
    __shared__ __bf16 sA[128 * 128];  // stage-0: [ci][n] n-swizzled; then weights; then sT
    __shared__ __bf16 sB[128 * 128];  // x tile transposed [n][ci] (staged once)
    const int t = threadIdx.x, lane = t & 63, wave = t >> 6;
    const int n0 = nt * 128;
    const float* xb = x + (size_t)b * 128 * 4096;
    // phase 0a: coalesced f32 read of x[ci][n0+n] -> sA[ci][n] (n XOR-swizzled by (ci>>3)&7)
    #pragma unroll
    for (int u = 0; u < 16; ++u) {
        int unit = t + u * 256;
        int ci = unit >> 5, n4 = (unit & 31) * 4;
        f32x4 v = *(const f32x4*)&xb[(size_t)ci * 4096 + n0 + n4];
        bf16x4 e;
        e[0] = f2bf(v[0]); e[1] = f2bf(v[1]); e[2] = f2bf(v[2]); e[3] = f2bf(v[3]);
        *(bf16x4*)&sA[ci * 128 + (n4 ^ (((ci >> 3) & 7) << 3))] = e;
    }
    __syncthreads();
    // phase 0b: transpose into sB[n][ci] (ci XOR-swizzled by swz(n,..))
    #pragma unroll
    for (int u = 0; u < 8; ++u) {
        int unit = t + u * 256;
        int cg = unit & 15, n = unit >> 4;
        bf16x8 o;
        #pragma unroll
        for (int j = 0; j < 8; ++j) {
            int ci = cg * 8 + j;
            o[j] = sA[ci * 128 + (n ^ (((ci >> 3) & 7) << 3))];
        }
        *(bf16x8*)&sB[n * 128 + swz(n, cg * 8)] = o;
    }
    for (int cot = 0; cot < 4; ++cot) {
        __syncthreads();
        #pragma unroll
        for (int u = 0; u < 8; ++u) {
            int unit = t + u * 256; int cc = unit & 15, r = unit >> 4;
            *(bf16x8*)&sA[r * 128 + swz(r, cc * 8)] =
                *(const bf16x8*)&wf[(size_t)(cot * 128 + r) * 128 + cc * 8];
        }
        __syncthreads();
        f32x4 acc[4][4];
        #pragma unroll
        for (int i = 0; i < 4; ++i)
            #pragma unroll
            for (int j = 0; j < 4; ++j) acc[i][j] = (f32x4){0.f, 0.f, 0.f, 0.f};
        mfma_tile<128, 4, 4>(sA, sB, acc, lane, (wave >> 1) * 64, (wave & 1) * 64);
        __syncthreads();
        __bf16* sT = sA;  // [n][128 co], co XOR-swizzled by (n&7)<<3
        #pragma unroll
        for (int i = 0; i < 4; ++i)
            #pragma unroll
            for (int r = 0; r < 4; ++r)
                #pragma unroll
                for (int j = 0; j < 4; ++j) {
                    int co = (wave >> 1) * 64 + i * 16 + ((lane >> 4) * 4 + r);
                    int n  = (wave & 1) * 64 + j * 16 + (lane & 15);
                    sT[n * 128 + (co ^ ((n & 7) << 3))] = f2bf(acc[i][j][r] + bias[cot * 128 + co]);
                }
        __syncthreads();
        #pragma unroll
        for (int u = 0; u < 8; ++u) {
            int unit = t + u * 256; int cc = unit & 15, n = unit >> 4;
            bf16x8 vv = *(bf16x8*)&sT[n * 128 + ((cc * 8) ^ ((n & 7) << 3))];
            *(bf16x8*)&qkv[((size_t)b * 4096 + n0 + n) * 512 + cot * 128 + cc * 8] = vv;
        }
    }
}

// ---------- K5: depthwise 3x3 + BN + relu, bf16 LDS + register row-reuse ----------
__global__ __launch_bounds__(256) void k5_dw(const __bf16* __restrict__ qkv,
                                             const float* __restrict__ wdw_t,
                                             const float* __restrict__ bdw,
                                             __bf16* __restrict__ dwo) {
    const int b = blockIdx.x, h0 = blockIdx.y * 4, cs = blockIdx.z * 32;
    __shared__ __bf16 sH[6][66][32];  // 25.3 KB
    const int t = threadIdx.x;
    const int w = t >> 2, cg = t & 3;  // cg: group of 8 channels
    #pragma unroll
    for (int row = 0; row < 6; ++row) {
        int h = h0 + row - 1;
        bf16x8 v;
        #pragma unroll
        for (int j = 0; j < 8; ++j) v[j] = bf_zero();
        if (h >= 0 && h < 64)
            v = *(const bf16x8*)&qkv[((size_t)b * 4096 + h * 64 + w) * 512 + cs + cg * 8];
        *(bf16x8*)&sH[row][w + 1][cg * 8] = v;
    }
    if (t < 192) {  // zero halo columns wz=0 and wz=65
        int row = t >> 5, c = t & 31;
        sH[row][0][c] = bf_zero();
        sH[row][65][c] = bf_zero();
    }
    float acc[4][8];
    {
        float bb[8];
        #pragma unroll
        for (int j = 0; j < 8; ++j) bb[j] = bdw[cs + cg * 8 + j];
        #pragma unroll
        for (int h = 0; h < 4; ++h)
            #pragma unroll
            for (int j = 0; j < 8; ++j) acc[h][j] = bb[j];
    }
    __syncthreads();
    #pragma unroll
    for (int dx = 0; dx < 3; ++dx) {
        f32x4 w0[3], w1[3];
        #pragma unroll
        for (int dy = 0; dy < 3; ++dy) {
            const float* wp = &wdw_t[(dy * 3 + dx) * 512 + cs + cg * 8];
            w0[dy] = *(const f32x4*)wp;
            w1[dy] = *(const f32x4*)(wp + 4);
        }
        float r[6][8];
        #pragma unroll
        for (int row = 0; row < 6; ++row) {
            bf16x8 v = *(const bf16x8*)&sH[row][w + dx][cg * 8];
            #pragma unroll
            for (int j = 0; j < 8; ++j) r[row][j] = bf2f(v[j]);
        }
        #pragma unroll
        for (int h = 0; h < 4; ++h)
            #pragma unroll
            for (int dy = 0; dy < 3; ++dy) {
                #pragma unroll
                for (int j = 0; j < 4; ++j) {
                    acc[h][j]     += w0[dy][j] * r[h + dy][j];
                    acc[h][4 + j] += w1[dy][j] * r[h + dy][4 + j];
                }
            }
    }
    #pragma unroll
    for (int h = 0; h < 4; ++h) {
        bf16x8 o;
        #pragma unroll
        for (int j = 0; j < 8; ++j) o[j] = f2bf(fmaxf(acc[h][j], 0.f));
        *(bf16x8*)&dwo[((size_t)b * 4096 + (h0 + h) * 64 + w) * 512 + cs + cg * 8] = o;
    }
}

// ---------- K67: fused pw GEMM + proj GEMM + gate; 512 threads (8 waves), 128co x 64n ----------
__global__ __launch_bounds__(512) void k67_fused(const __bf16* __restrict__ dws,
                                                 const __bf16* __restrict__ wpw,
                                                 const float* __restrict__ bias_pw,
                                                 const __bf16* __restrict__ qkv,
                                                 const __bf16* __restrict__ wproj,
                                                 const float* __restrict__ bias_proj,
                                                 const float* __restrict__ xrc,
                                                 float* __restrict__ out) {
    const int b = blockIdx.x, nt = blockIdx.y;   // nt = h row (64 pixels)
    __shared__ __bf16 sA[128 * 128];
    __shared__ __bf16 sB[64 * 128];
    const int t = threadIdx.x, lane = t & 63, wave = t >> 6;   // 8 waves
    const int arow0 = (wave & 3) * 32, brow0 = (wave >> 2) * 32;  // 4x2 quadrants of 32x32
    const float* xr = xrc + (size_t)(b * 2 + 0) * 64 * 256;
    const float* xc = xrc + (size_t)(b * 2 + 1) * 64 * 256;
    f32x4 acc_pw[2][2], acc_pj[2][2];
    #pragma unroll
    for (int i = 0; i < 2; ++i)
        #pragma unroll
        for (int j = 0; j < 2; ++j) {
            acc_pw[i][j] = (f32x4){0.f, 0.f, 0.f, 0.f};
            acc_pj[i][j] = (f32x4){0.f, 0.f, 0.f, 0.f};
        }
    // phase 1: pw GEMM, K=512; both operands via async global_load_lds (pre-swizzled src)
    for (int kc = 0; kc < 4; ++kc) {
        __syncthreads();
        #pragma unroll
        for (int u = 0; u < 4; ++u) {          // sA: 32 chunks of 1KB over 8 waves
            int r0 = (wave * 4 + u) * 4;
            int row = r0 + (lane >> 4);
            int slot = (lane & 15) ^ (row & 7);
            gload_lds16(&wpw[(size_t)row * 512 + kc * 128 + slot * 8], &sA[r0 * 128]);
        }
        #pragma unroll
        for (int u = 0; u < 2; ++u) {          // sB: 16 chunks of 1KB
            int r0 = (wave * 2 + u) * 4;
            int row = r0 + (lane >> 4);
            int slot = (lane & 15) ^ (row & 7);
            gload_lds16(&dws[((size_t)b * 4096 + nt * 64 + row) * 512 + kc * 128 + slot * 8],
                        &sB[r0 * 128]);
        }
        __syncthreads();
        mfma_tile<128, 2, 2>(sA, sB, acc_pw, lane, arow0, brow0);
    }
    // phase 2: proj GEMM on relu(v + xx_row + xx_col), K=256 (sA async; sB computed)
    for (int kc = 0; kc < 2; ++kc) {
        __syncthreads();
        #pragma unroll
        for (int u = 0; u < 4; ++u) {
            int r0 = (wave * 4 + u) * 4;
            int row = r0 + (lane >> 4);
            int slot = (lane & 15) ^ (row & 7);
            gload_lds16(&wproj[(size_t)row * 256 + kc * 128 + slot * 8], &sA[r0 * 128]);
        }
        #pragma unroll
        for (int u = 0; u < 2; ++u) {          // 1024 units over 512 threads
            int unit = t + u * 512; int cc = unit & 15, r = unit >> 4;
            int n = nt * 64 + r, h = n >> 6, ww = n & 63;
            int k = kc * 128 + cc * 8;
            bf16x8 v8 = *(const bf16x8*)&qkv[((size_t)b * 4096 + n) * 512 + 256 + k];
            f32x4 a0 = *(const f32x4*)&xr[h * 256 + k];
            f32x4 a1 = *(const f32x4*)&xr[h * 256 + k + 4];
            f32x4 c0 = *(const f32x4*)&xc[ww * 256 + k];
            f32x4 c1 = *(const f32x4*)&xc[ww * 256 + k + 4];
            bf16x8 o;
            o[0] = f2bf(fmaxf(bf2f(v8[0]) + a0[0] + c0[0], 0.f));
            o[1] = f2bf(fmaxf(bf2f(v8[1]) + a0[1] + c0[1], 0.f));
            o[2] = f2bf(fmaxf(bf2f(v8[2]) + a0[2] + c0[2], 0.f));
            o[3] = f2bf(fmaxf(bf2f(v8[3]) + a0[3] + c0[3], 0.f));
            o[4] = f2bf(fmaxf(bf2f(v8[4]) + a1[0] + c1[0], 0.f));
            o[5] = f2bf(fmaxf(bf2f(v8[5]) + a1[1] + c1[1], 0.f));
            o[6] = f2bf(fmaxf(bf2f(v8[6]) + a1[2] + c1[2], 0.f));
            o[7] = f2bf(fmaxf(bf2f(v8[7]) + a1[3] + c1[3], 0.f));
            *(bf16x8*)&sB[r * 128 + swz(r, cc * 8)] = o;
        }
        __syncthreads();
        mfma_tile<128, 2, 2>(sA, sB, acc_pj, lane, arow0, brow0);
    }
    // epilogue: out = h_sigmoid(proj) * pw   (both still in registers)
    #pragma unroll
    for (int i = 0; i < 2; ++i)
        #pragma unroll
        for (int r = 0; r < 4; ++r)
            #pragma unroll
            for (int j = 0; j < 2; ++j) {
                int co = arow0 + i * 16 + ((lane >> 4) * 4 + r);
                int n  = brow0 + j * 16 + (lane & 15);
                size_t idx = ((size_t)b * 128 + co) * 4096 + nt * 64 + n;
                float p = acc_pj[i][j][r] + bias_proj[co];
                float hs = fminf(fmaxf(p + 3.f, 0.f), 6.f) * (1.f / 6.f);
                out[idx] = hs * (acc_pw[i][j][r] + bias_pw[co]);
            }
}

// ---------- workspace layout (bytes) ----------
static constexpr size_t OFF_WF_QKV = 0;                        // 131072
static constexpr size_t OFF_WPW    = 131072;                   // 131072
static constexpr size_t OFF_WPROJ  = 262144;                   // 65536
static constexpr size_t OFF_WRC    = 327680;                   // 262144 (bf16 [2][256][256])
static constexpr size_t OFF_WDW    = 589824;                   // wdw_t[9][512] f32 (padded)
static constexpr size_t OFF_BQKV   = 610304;
static constexpr size_t OFF_BDW    = 612352;
static constexpr size_t OFF_BPW    = 614400;
static constexpr size_t OFF_BROW   = 615424;
static constexpr size_t OFF_BCOL   = 616448;
static constexpr size_t OFF_BPROJ  = 617472;
static constexpr size_t OFF_XMEANT = 17395712;                 // 1048576
static constexpr size_t OFF_QM     = 18444288;                 // 4194304
static constexpr size_t OFF_ATTNT  = 22638592;                 // 1048576 (bf16)
static constexpr size_t OFF_XRC    = 23687168;                 // 2097152
static constexpr size_t OFF_QKV    = 25784320;                 // 67108864
static constexpr size_t OFF_DWOUT  = 92893184;                 // 67108864

extern "C" void kernel_launch(void* const* d_in, const int* in_sizes, int n_in,
                              void* d_out, int out_size, void* d_ws, size_t ws_size,
                              hipStream_t stream) {
    const float* x     = (const float*)d_in[0];
    const float* wq    = (const float*)d_in[1];
    const float* sq    = (const float*)d_in[2];
    const float* bq    = (const float*)d_in[3];
    const float* wk    = (const float*)d_in[4];
    const float* sk    = (const float*)d_in[5];
    const float* bk    = (const float*)d_in[6];
    const float* wv    = (const float*)d_in[7];
    const float* sv    = (const float*)d_in[8];
    const float* bv    = (const float*)d_in[9];
    const float* wdw   = (const float*)d_in[10];
    const float* sdw   = (const float*)d_in[11];
    const float* bdw   = (const float*)d_in[12];
    const float* wpw   = (const float*)d_in[13];
    const float* spw   = (const float*)d_in[14];
    const float* bpw   = (const float*)d_in[15];
    const float* wrow  = (const float*)d_in[16];
    const float* srow  = (const float*)d_in[17];
    const float* brow  = (const float*)d_in[18];
    const float* wcol  = (const float*)d_in[19];
    const float* scol  = (const float*)d_in[20];
    const float* bcol  = (const float*)d_in[21];
    const float* wproj = (const float*)d_in[22];
    const float* sproj = (const float*)d_in[23];
    const float* bproj = (const float*)d_in[24];
    const float* pe_rq = (const float*)d_in[25];
    const float* pe_rk = (const float*)d_in[26];
    const float* pe_cq = (const float*)d_in[27];
    const float* pe_ck = (const float*)d_in[28];

    char* ws = (char*)d_ws;
    __bf16* wf_qkv   = (__bf16*)(ws + OFF_WF_QKV);
    __bf16* wpw_f    = (__bf16*)(ws + OFF_WPW);
    __bf16* wproj_f  = (__bf16*)(ws + OFF_WPROJ);
    __bf16* wrc_f    = (__bf16*)(ws + OFF_WRC);
    float* wdw_t     = (float*)(ws + OFF_WDW);
    float* bias_qkv  = (float*)(ws + OFF_BQKV);
    float* bias_dw   = (float*)(ws + OFF_BDW);
    float* bias_pw   = (float*)(ws + OFF_BPW);
    float* bias_row  = (float*)(ws + OFF_BROW);
    float* bias_col  = (float*)(ws + OFF_BCOL);
    float* bias_proj = (float*)(ws + OFF_BPROJ);
    float* xmT       = (float*)(ws + OFF_XMEANT);
    float* qm        = (float*)(ws + OFF_QM);
    __bf16* attnT    = (__bf16*)(ws + OFF_ATTNT);
    float* xrc       = (float*)(ws + OFF_XRC);
    __bf16* qkv      = (__bf16*)(ws + OFF_QKV);
    __bf16* dwout    = (__bf16*)(ws + OFF_DWOUT);

    k0_fold<<<1170, 256, 0, stream>>>(wq, sq, bq, wk, sk, bk, wv, sv, bv,
                                      wdw, sdw, bdw, wpw, spw, bpw,
                                      wrow, srow, brow, wcol, scol, bcol,
                                      wproj, sproj, bproj,
                                      wf_qkv, bias_qkv, wdw_t, bias_dw, wpw_f, bias_pw,
                                      wrc_f, bias_row, bias_col, wproj_f, bias_proj);
    kM_xmean<<<dim3(16, 32), 256, 0, stream>>>(x, xmT);
    kQM<<<dim3(16, 2, 4), 256, 0, stream>>>(wf_qkv, bias_qkv, xmT, qm);
    k3_attn<<<dim3(16, 2, 8), 64, 0, stream>>>(qm, pe_rq, pe_rk, pe_cq, pe_ck, attnT);
    k4_rcconv<<<dim3(16, 2, 2), 256, 0, stream>>>(attnT, wrc_f, bias_row, bias_col, xrc);
    k1_qkv<<<dim3(16, 32), 256, 0, stream>>>(x, wf_qkv, bias_qkv, qkv);
    k5_dw<<<dim3(16, 16, 16), 256, 0, stream>>>(qkv, wdw_t, bias_dw, dwout);
    k67_fused<<<dim3(16, 64), 512, 0, stream>>>(dwout, wpw_f, bias_pw, qkv, wproj_f,
                                                bias_proj, xrc, (float*)d_out);
}